// Round 1
// baseline (1190.941 us; speedup 1.0000x reference)
//
#include <hip/hip_runtime.h>
#include <hip/hip_fp16.h>
#include <cstdint>
#include <cstddef>

using u16 = unsigned short;
using u32 = unsigned int;

typedef _Float16 half8 __attribute__((ext_vector_type(8)));
typedef float f32x4 __attribute__((ext_vector_type(4)));

static inline int cdiv(int a, int b) { return (a + b - 1) / b; }

// ---------------------------------------------------------------------------
// Small conversion / prep kernels
// ---------------------------------------------------------------------------

__global__ void cvt_f32_f16_k(const float* __restrict__ src, u16* __restrict__ dst, size_t n4) {
    size_t i = (size_t)blockIdx.x * 256 + threadIdx.x;
    if (i >= n4) return;
    float4 v = *(const float4*)(src + i * 4);
    union { uint2 u; _Float16 h[4]; } o;
    o.h[0] = (_Float16)v.x; o.h[1] = (_Float16)v.y;
    o.h[2] = (_Float16)v.z; o.h[3] = (_Float16)v.w;
    *(uint2*)(dst + i * 4) = o.u;
}

// W_cat panel layout per layer: [552 panels][256 cols][8 k] f16, K=4416 padded.
// k<4096: W_rule[l][k>>8][k&255][o]; k<4352: W_self[l][k-4096][o]; k<4368: b_rule[l][k-4352][o]; else 0
__global__ void build_wcat_k(const float* __restrict__ Wr, const float* __restrict__ Ws,
                             const float* __restrict__ br, u16* __restrict__ dst) {
    size_t t = (size_t)blockIdx.x * 256 + threadIdx.x;
    const size_t PL = 552u * 256u * 8u;  // per-layer elements
    if (t >= 3 * PL) return;
    int l = (int)(t / PL);
    size_t rem = t - (size_t)l * PL;
    int kp = (int)(rem >> 11);
    int o = (int)((rem >> 3) & 255);
    int e = (int)(rem & 7);
    int k = kp * 8 + e;
    float v;
    if (k < 4096)      v = Wr[((((size_t)l * 16 + (k >> 8)) * 256) + (k & 255)) * 256 + o];
    else if (k < 4352) v = Ws[(((size_t)l * 256) + (k - 4096)) * 256 + o];
    else if (k < 4368) v = br[(((size_t)l * 16) + (k - 4352)) * 256 + o];
    else               v = 0.f;
    union { u16 u; _Float16 h; } c; c.h = (_Float16)v;
    dst[t] = c.u;
}

// generic panelizer: src [K][M] f32 -> dst [K/8][M][8] f16 (K multiple of 8)
__global__ void panelize_k(const float* __restrict__ src, u16* __restrict__ dst, int K, int M) {
    size_t t = (size_t)blockIdx.x * 256 + threadIdx.x;
    if (t >= (size_t)K * M) return;
    int e = (int)(t & 7);
    int o = (int)((t >> 3) % M);
    int kp = (int)(t / ((size_t)8 * M));
    int k = kp * 8 + e;
    union { u16 u; _Float16 h; } c; c.h = (_Float16)src[(size_t)k * M + o];
    dst[t] = c.u;
}

// membership precompute: inv_s2, c*inv_s2, sum(c^2*inv_s2) per (l,r)
__global__ void pc_build_k(const float* __restrict__ centers, const float* __restrict__ logsig,
                           float* __restrict__ pcinv, float* __restrict__ pcci,
                           float* __restrict__ pccc) {
    int lr = blockIdx.x;       // 0..47 = l*16+r
    int i = threadIdx.x;       // 256
    size_t idx = (size_t)lr * 256 + i;
    float ls = logsig[idx];
    float inv = expf(-2.f * ls);
    float c = centers[idx];
    pcinv[idx] = inv;
    pcci[idx] = c * inv;
    __shared__ float sm[256];
    sm[i] = c * c * inv;
    __syncthreads();
    for (int s = 128; s > 0; s >>= 1) { if (i < s) sm[i] += sm[i + s]; __syncthreads(); }
    if (i == 0) pccc[lr] = sm[0];
}

// ---------------------------------------------------------------------------
// CSR build (count -> scan -> scatter)
// ---------------------------------------------------------------------------

__global__ void deg_count_k(const int* __restrict__ dst, int* __restrict__ deg, int E) {
    int e = blockIdx.x * 256 + threadIdx.x;
    if (e < E) atomicAdd(&deg[dst[e]], 1);
}

__global__ void csr_scan_k(const int* __restrict__ deg, int* __restrict__ indptr,
                           int* __restrict__ cursor, float* __restrict__ deginv, int n) {
    const int tid = threadIdx.x;   // 1024 threads, 1 block
    const int chunk = (n + 1023) >> 10;
    int s0 = tid * chunk, s1 = s0 + chunk; if (s1 > n) s1 = n; if (s0 > n) s0 = n;
    int tot = 0;
    for (int i = s0; i < s1; ++i) tot += deg[i];
    __shared__ int sm[1024];
    sm[tid] = tot; __syncthreads();
    for (int off = 1; off < 1024; off <<= 1) {
        int t = (tid >= off) ? sm[tid - off] : 0;
        __syncthreads(); sm[tid] += t; __syncthreads();
    }
    int base = sm[tid] - tot;  // exclusive prefix
    for (int i = s0; i < s1; ++i) {
        int d = deg[i];
        indptr[i] = base; cursor[i] = base;
        deginv[i] = 1.f / (float)(d > 1 ? d : 1);
        base += d;
    }
    if (tid == 1023) indptr[n] = sm[1023];
}

__global__ void edge_scatter_k(const int* __restrict__ src, const int* __restrict__ dst,
                               int* __restrict__ cursor, int* __restrict__ ssrc, int E) {
    int e = blockIdx.x * 256 + threadIdx.x;
    if (e < E) {
        int d = dst[e];
        int pos = atomicAdd(&cursor[d], 1);
        ssrc[pos] = src[e];
    }
}

// ---------------------------------------------------------------------------
// Membership: mu[n,r] = softmax-ish normalized Gaussian firing. Sets per-128-row
// block flag iff any firing > 0 (in this data exp(-~150) underflows to 0 -> no flags).
// ---------------------------------------------------------------------------

__global__ void membership_k(const u16* __restrict__ h16,
                             const float* __restrict__ pcinv, const float* __restrict__ pcci,
                             const float* __restrict__ pccc,
                             u16* __restrict__ mu16, int* __restrict__ bflag, int n) {
    int lane = threadIdx.x & 63, wave = threadIdx.x >> 6;
    int node = blockIdx.x * 4 + wave;
    if (node >= n) return;
    int c = lane * 4;
    union { uint2 u; _Float16 h[4]; } hv;
    hv.u = *(const uint2*)(h16 + (size_t)node * 256 + c);
    float h0 = (float)hv.h[0], h1 = (float)hv.h[1], h2 = (float)hv.h[2], h3 = (float)hv.h[3];
    float f[16]; float s = 0.f;
#pragma unroll
    for (int r = 0; r < 16; ++r) {
        float4 inv = *(const float4*)(pcinv + r * 256 + c);
        float4 ci  = *(const float4*)(pcci + r * 256 + c);
        float t = h0 * (h0 * inv.x - 2.f * ci.x) + h1 * (h1 * inv.y - 2.f * ci.y)
                + h2 * (h2 * inv.z - 2.f * ci.z) + h3 * (h3 * inv.w - 2.f * ci.w);
#pragma unroll
        for (int off = 32; off; off >>= 1) t += __shfl_xor(t, off);
        float d = t + pccc[r];
        float fr = expf(-0.5f * d);
        f[r] = fr; s += fr;
    }
    float is = 1.f / (s + 1e-12f);
    if (lane < 16) {
        union { u16 u; _Float16 h; } c2; c2.h = (_Float16)(f[lane] * is);
        mu16[(size_t)node * 16 + lane] = c2.u;
    }
    if (lane == 0 && s > 0.f) atomicOr(&bflag[node >> 7], 1);
}

// ---------------------------------------------------------------------------
// Neighbor mean (only for flagged 128-row blocks)
// ---------------------------------------------------------------------------

__global__ void agg_k(const u16* __restrict__ h16, const int* __restrict__ indptr,
                      const int* __restrict__ ssrc, const float* __restrict__ deginv,
                      const int* __restrict__ bflag, u16* __restrict__ agg16, int n) {
    int lane = threadIdx.x & 63, wave = threadIdx.x >> 6;
    int node = blockIdx.x * 4 + wave;
    if (node >= n) return;
    if (bflag[node >> 7] == 0) return;
    int j0 = indptr[node], j1 = indptr[node + 1];
    float a0 = 0, a1 = 0, a2 = 0, a3 = 0;
    for (int j = j0; j < j1; ++j) {
        int sN = ssrc[j];
        union { uint2 u; _Float16 h[4]; } hv;
        hv.u = *(const uint2*)(h16 + (size_t)sN * 256 + lane * 4);
        a0 += (float)hv.h[0]; a1 += (float)hv.h[1];
        a2 += (float)hv.h[2]; a3 += (float)hv.h[3];
    }
    float di = deginv[node];
    union { uint2 u; _Float16 h[4]; } o;
    o.h[0] = (_Float16)(a0 * di); o.h[1] = (_Float16)(a1 * di);
    o.h[2] = (_Float16)(a2 * di); o.h[3] = (_Float16)(a3 * di);
    *(uint2*)(agg16 + (size_t)node * 256 + lane * 4) = o.u;
}

// ---------------------------------------------------------------------------
// Unified f16 MFMA GEMM. 128x128 tile, BK=64, 256 threads (4 waves of 64x64).
// LDS fragment-native layout [p=k/8][row|col][8k].
// MODE 0: h = relu(x16 @ Winp + b_in)   (K=128)  -> h f32 + h f16
// MODE 1: pre = [mu*agg | h | mu]@Wcat + b_self  (K=4416, fuzzy section skippable)
// MODE 2: q16 = relu(h16 @ Wh1p + b_h1) (K=256)
// ---------------------------------------------------------------------------

template <int MODE, int NCHUNK>
__launch_bounds__(256, 2)
__global__ void gemm_k(const u16* __restrict__ A, const u16* __restrict__ A2,
                       const u16* __restrict__ MU, const u16* __restrict__ Bp,
                       const float* __restrict__ bias, const int* __restrict__ bflag,
                       float* __restrict__ outF, u16* __restrict__ outH,
                       int nrows, int mcols, int astride) {
    __shared__ __align__(16) u16 lA[8192];  // [8][128][8] f16 = 16KB
    __shared__ __align__(16) u16 lB[8192];
    const int tid = threadIdx.x;
    const int row0 = blockIdx.x * 128;
    const int c0 = blockIdx.y * 128;
    const int lane = tid & 63;
    const int q = lane >> 4, mm = lane & 15;
    const int wave = tid >> 6;
    const int wm = wave >> 1, wn = wave & 1;

    f32x4 acc[4][4];
#pragma unroll
    for (int i = 0; i < 4; ++i)
#pragma unroll
        for (int j = 0; j < 4; ++j) acc[i][j] = (f32x4){0.f, 0.f, 0.f, 0.f};

    int cb = 0;
    if (MODE == 1) {
        if (bflag[blockIdx.x] == 0) cb = 64;  // mu==0 for every row in block: fuzzy section is exactly 0
    }

    for (; cb < NCHUNK; ++cb) {
        // stage B tile (64k x 128cols)
#pragma unroll
        for (int it = 0; it < 4; ++it) {
            int idx = it * 256 + tid;
            int p = idx >> 7, col = idx & 127;
            uint4 v = *(const uint4*)(Bp + (((size_t)(cb * 8 + p)) * mcols + c0 + col) * 8);
            *(uint4*)(lB + (size_t)idx * 8) = v;
        }
        // stage A tile (128rows x 64k)
#pragma unroll
        for (int it = 0; it < 4; ++it) {
            int idx = it * 256 + tid;
            int p = idx >> 7, row = idx & 127;
            int grow = row0 + row; if (grow >= nrows) grow = nrows - 1;
            uint4 v;
            if (MODE != 1) {
                v = *(const uint4*)(A + (size_t)grow * astride + cb * 64 + p * 8);
            } else {
                if (cb < 64) {
                    int r = cb >> 2;
                    int i0 = ((cb & 3) << 6) + (p << 3);
                    v = *(const uint4*)(A + (size_t)grow * 256 + i0);
                    union { u16 u; _Float16 h; } mu; mu.u = MU[(size_t)grow * 16 + r];
                    union { uint4 u4; _Float16 h[8]; } w; w.u4 = v;
#pragma unroll
                    for (int j = 0; j < 8; ++j) w.h[j] = w.h[j] * mu.h;
                    v = w.u4;
                } else if (cb < 68) {
                    int i0 = ((cb - 64) << 6) + (p << 3);
                    v = *(const uint4*)(A2 + (size_t)grow * 256 + i0);
                } else {
                    int j0 = p << 3;
                    if (j0 < 16) v = *(const uint4*)(MU + (size_t)grow * 16 + j0);
                    else v = (uint4){0, 0, 0, 0};
                }
            }
            *(uint4*)(lA + (size_t)idx * 8) = v;
        }
        __syncthreads();
#pragma unroll
        for (int kc = 0; kc < 2; ++kc) {
            int pp = kc * 4 + q;
            half8 af[4], bf[4];
#pragma unroll
            for (int mt = 0; mt < 4; ++mt)
                af[mt] = *(const half8*)(lA + ((size_t)pp * 128 + wm * 64 + mt * 16 + mm) * 8);
#pragma unroll
            for (int nt = 0; nt < 4; ++nt)
                bf[nt] = *(const half8*)(lB + ((size_t)pp * 128 + wn * 64 + nt * 16 + mm) * 8);
#pragma unroll
            for (int mt = 0; mt < 4; ++mt)
#pragma unroll
                for (int nt = 0; nt < 4; ++nt)
                    acc[mt][nt] = __builtin_amdgcn_mfma_f32_16x16x32_f16(af[mt], bf[nt], acc[mt][nt], 0, 0, 0);
        }
        __syncthreads();
    }

    // epilogue: C/D layout col=lane&15, row=q*4+reg
#pragma unroll
    for (int mt = 0; mt < 4; ++mt) {
#pragma unroll
        for (int nt = 0; nt < 4; ++nt) {
#pragma unroll
            for (int r = 0; r < 4; ++r) {
                int grow = row0 + wm * 64 + mt * 16 + q * 4 + r;
                int gcol = c0 + wn * 64 + nt * 16 + mm;
                if (grow < nrows) {
                    float v = acc[mt][nt][r] + bias[gcol];
                    if (MODE == 0) {
                        v = fmaxf(v, 0.f);
                        outF[(size_t)grow * mcols + gcol] = v;
                        union { u16 u; _Float16 h; } c; c.h = (_Float16)v;
                        outH[(size_t)grow * mcols + gcol] = c.u;
                    } else if (MODE == 1) {
                        outF[(size_t)grow * mcols + gcol] = v;
                    } else {
                        v = fmaxf(v, 0.f);
                        union { u16 u; _Float16 h; } c; c.h = (_Float16)v;
                        outH[(size_t)grow * mcols + gcol] = c.u;
                    }
                }
            }
        }
    }
}

// ---------------------------------------------------------------------------
// BatchNorm (stats over N per channel) + fused residual relu update
// ---------------------------------------------------------------------------

__global__ void bn_stats_k(const float* __restrict__ pre, float* __restrict__ sums, int n) {
    int col = threadIdx.x;  // 256
    int r0 = blockIdx.x * 512, r1 = r0 + 512; if (r1 > n) r1 = n;
    float s = 0.f, ss = 0.f;
    for (int r = r0; r < r1; ++r) {
        float v = pre[(size_t)r * 256 + col];
        s += v; ss += v * v;
    }
    atomicAdd(&sums[col], s);
    atomicAdd(&sums[256 + col], ss);
}

__global__ void bn_final_k(const float* __restrict__ sums, const float* __restrict__ gamma,
                           const float* __restrict__ beta, float* __restrict__ ab, int n) {
    int col = threadIdx.x;
    float mean = sums[col] / (float)n;
    float var = sums[256 + col] / (float)n - mean * mean;
    float al = gamma[col] * rsqrtf(var + 1e-5f);
    ab[col] = al;
    ab[256 + col] = beta[col] - mean * al;
}

__global__ void update_k(const float* __restrict__ pre, const float* __restrict__ ab,
                         float* __restrict__ h, u16* __restrict__ h16, int n) {
    size_t i4 = (size_t)blockIdx.x * 256 + threadIdx.x;
    if (i4 >= (size_t)n * 64) return;
    int c4 = (int)(i4 & 63) * 4;
    float4 p = *(const float4*)(pre + i4 * 4);
    float4 al = *(const float4*)(ab + c4);
    float4 sh = *(const float4*)(ab + 256 + c4);
    float4 hv = *(const float4*)(h + i4 * 4);
    float v0 = hv.x + fmaxf(p.x * al.x + sh.x, 0.f);
    float v1 = hv.y + fmaxf(p.y * al.y + sh.y, 0.f);
    float v2 = hv.z + fmaxf(p.z * al.z + sh.z, 0.f);
    float v3 = hv.w + fmaxf(p.w * al.w + sh.w, 0.f);
    *(float4*)(h + i4 * 4) = (float4){v0, v1, v2, v3};
    union { uint2 u; _Float16 hh[4]; } o;
    o.hh[0] = (_Float16)v0; o.hh[1] = (_Float16)v1;
    o.hh[2] = (_Float16)v2; o.hh[3] = (_Float16)v3;
    *(uint2*)(h16 + i4 * 4) = o.u;
}

// ---------------------------------------------------------------------------
// Head: logits = q16 @ W_h2 + b_h2, softmax. One thread per node, W_h2 in LDS.
// ---------------------------------------------------------------------------

__launch_bounds__(256)
__global__ void head_k(const u16* __restrict__ q16, const float* __restrict__ Wh2,
                       const float* __restrict__ bh2, float* __restrict__ out, int n) {
    __shared__ float W[5160];  // 128*40 + 40
    for (int i = threadIdx.x; i < 5160; i += 256)
        W[i] = (i < 5120) ? Wh2[i] : bh2[i - 5120];
    __syncthreads();
    int node = blockIdx.x * 256 + threadIdx.x;
    if (node >= n) return;
    float acc[40];
#pragma unroll
    for (int o = 0; o < 40; ++o) acc[o] = W[5120 + o];
    const u32* qp = (const u32*)(q16 + (size_t)node * 128);
    for (int k2 = 0; k2 < 64; ++k2) {
        union { u32 u; _Float16 h[2]; } qq; qq.u = qp[k2];
        float a = (float)qq.h[0], b = (float)qq.h[1];
        const float* w0 = W + (k2 * 2) * 40;
        const float* w1 = w0 + 40;
#pragma unroll
        for (int o = 0; o < 40; ++o) acc[o] += a * w0[o] + b * w1[o];
    }
    float mx = acc[0];
#pragma unroll
    for (int o = 1; o < 40; ++o) mx = fmaxf(mx, acc[o]);
    float s = 0.f;
#pragma unroll
    for (int o = 0; o < 40; ++o) { float e = expf(acc[o] - mx); acc[o] = e; s += e; }
    float is = 1.f / s;
    float* op = out + (size_t)node * 40;
#pragma unroll
    for (int o = 0; o < 40; ++o) op[o] = acc[o] * is;
}

// ---------------------------------------------------------------------------
// Launch
// ---------------------------------------------------------------------------

extern "C" void kernel_launch(void* const* d_in, const int* in_sizes, int n_in,
                              void* d_out, int out_size, void* d_ws, size_t ws_size,
                              hipStream_t stream) {
    const float* x       = (const float*)d_in[0];
    const int*   ei      = (const int*)d_in[1];
    const float* W_in    = (const float*)d_in[2];
    const float* b_in    = (const float*)d_in[3];
    const float* centers = (const float*)d_in[4];
    const float* logsig  = (const float*)d_in[5];
    const float* W_rule  = (const float*)d_in[6];
    const float* b_rule  = (const float*)d_in[7];
    const float* W_self  = (const float*)d_in[8];
    const float* b_self  = (const float*)d_in[9];
    const float* gamma   = (const float*)d_in[10];
    const float* beta    = (const float*)d_in[11];
    const float* W_h1    = (const float*)d_in[12];
    const float* b_h1    = (const float*)d_in[13];
    const float* W_h2    = (const float*)d_in[14];
    const float* b_h2    = (const float*)d_in[15];

    const int N = in_sizes[0] / 128;
    const int E = in_sizes[1] / 2;
    const int* e_src = ei;
    const int* e_dst = ei + E;

    char* w = (char*)d_ws;
    size_t off = 0;
    auto alloc = [&](size_t bytes) -> void* {
        void* p = w + off;
        off = (off + bytes + 255) & ~(size_t)255;
        return p;
    };

    u16*   x16    = (u16*)  alloc((size_t)N * 128 * 2);
    float* h      = (float*)alloc((size_t)N * 256 * 4);
    u16*   h16    = (u16*)  alloc((size_t)N * 256 * 2);
    float* pre    = (float*)alloc((size_t)N * 256 * 4);
    u16*   agg16  = (u16*)  alloc((size_t)N * 256 * 2);
    u16*   mu16   = (u16*)  alloc((size_t)N * 16 * 2);
    u16*   q16    = (u16*)  alloc((size_t)N * 128 * 2);
    u16*   wcat   = (u16*)  alloc((size_t)3 * 552 * 256 * 8 * 2);
    u16*   winp   = (u16*)  alloc((size_t)16 * 256 * 8 * 2);
    u16*   wh1p   = (u16*)  alloc((size_t)32 * 128 * 8 * 2);
    float* pcinv  = (float*)alloc((size_t)48 * 256 * 4);
    float* pcci   = (float*)alloc((size_t)48 * 256 * 4);
    float* pccc   = (float*)alloc((size_t)48 * 4);
    int*   deg    = (int*)  alloc((size_t)N * 4);
    int*   indptr = (int*)  alloc((size_t)(N + 1) * 4);
    int*   cursor = (int*)  alloc((size_t)N * 4);
    float* deginv = (float*)alloc((size_t)N * 4);
    int*   ssrc   = (int*)  alloc((size_t)E * 4);
    char*  zeros  = (char*) alloc((size_t)2 * 3 * 512 * 4);  // bflag[3][512] + bnsums[3][512]
    int*   bflag  = (int*)zeros;
    float* bnsums = (float*)(zeros + 3 * 512 * 4);
    float* bnab   = (float*)alloc((size_t)3 * 512 * 4);

    // zero-init (ws is poisoned before every call)
    hipMemsetAsync(deg, 0, (size_t)N * 4, stream);
    hipMemsetAsync(zeros, 0, (size_t)2 * 3 * 512 * 4, stream);

    const int gx = cdiv(N, 128);  // 391 row blocks

    // conversions / weight prep
    cvt_f32_f16_k<<<cdiv(N * 32, 256), 256, 0, stream>>>(x, x16, (size_t)N * 32);
    build_wcat_k<<<cdiv(3 * 4416 * 256, 256), 256, 0, stream>>>(W_rule, W_self, b_rule, wcat);
    panelize_k<<<cdiv(128 * 256, 256), 256, 0, stream>>>(W_in, winp, 128, 256);
    panelize_k<<<cdiv(256 * 128, 256), 256, 0, stream>>>(W_h1, wh1p, 256, 128);
    pc_build_k<<<48, 256, 0, stream>>>(centers, logsig, pcinv, pcci, pccc);

    // CSR
    deg_count_k<<<cdiv(E, 256), 256, 0, stream>>>(e_dst, deg, E);
    csr_scan_k<<<1, 1024, 0, stream>>>(deg, indptr, cursor, deginv, N);
    edge_scatter_k<<<cdiv(E, 256), 256, 0, stream>>>(e_src, e_dst, cursor, ssrc, E);

    // input layer: h = relu(x @ W_in + b_in)
    gemm_k<0, 2><<<dim3(gx, 2), 256, 0, stream>>>(x16, nullptr, nullptr, winp, b_in,
                                                  nullptr, h, h16, N, 256, 128);

    for (int l = 0; l < 3; ++l) {
        int* bf = bflag + l * 512;
        membership_k<<<cdiv(N, 4), 256, 0, stream>>>(h16, pcinv + (size_t)l * 16 * 256,
                                                     pcci + (size_t)l * 16 * 256,
                                                     pccc + l * 16, mu16, bf, N);
        agg_k<<<cdiv(N, 4), 256, 0, stream>>>(h16, indptr, ssrc, deginv, bf, agg16, N);
        gemm_k<1, 69><<<dim3(gx, 2), 256, 0, stream>>>(agg16, h16, mu16,
                                                       wcat + (size_t)l * 552 * 256 * 8,
                                                       b_self + l * 256, bf, pre, nullptr,
                                                       N, 256, 0);
        bn_stats_k<<<cdiv(N, 512), 256, 0, stream>>>(pre, bnsums + l * 512, N);
        bn_final_k<<<1, 256, 0, stream>>>(bnsums + l * 512, gamma + l * 256, beta + l * 256,
                                          bnab + l * 512, N);
        update_k<<<cdiv(N * 64, 256), 256, 0, stream>>>(pre, bnab + l * 512, h, h16, N);
    }

    // head
    gemm_k<2, 4><<<dim3(gx, 1), 256, 0, stream>>>(h16, nullptr, nullptr, wh1p, b_h1,
                                                  nullptr, nullptr, q16, N, 128, 256);
    head_k<<<cdiv(N, 256), 256, 0, stream>>>(q16, W_h2, b_h2, (float*)d_out, N);
}

// Round 2
// 753.564 us; speedup vs baseline: 1.5804x; 1.5804x over previous
//
#include <hip/hip_runtime.h>
#include <hip/hip_fp16.h>
#include <cstdint>
#include <cstddef>

using u16 = unsigned short;
using u32 = unsigned int;

typedef _Float16 half8 __attribute__((ext_vector_type(8)));
typedef float f32x4 __attribute__((ext_vector_type(4)));

static inline int cdiv(int a, int b) { return (a + b - 1) / b; }

// ===========================================================================
// prep_k: fused zero-init + f16 cast + weight panelization + rule precompute.
// Roles selected by blockIdx range (uniform per block).
// ===========================================================================

__global__ void prep_k(const float* __restrict__ x, const float* __restrict__ Wr,
                       const float* __restrict__ Ws, const float* __restrict__ br,
                       const float* __restrict__ W_in, const float* __restrict__ W_h1,
                       const float* __restrict__ centers, const float* __restrict__ logsig,
                       u16* __restrict__ x16, u16* __restrict__ wcat,
                       u16* __restrict__ winp, u16* __restrict__ wh1p,
                       float* __restrict__ pcinv, float* __restrict__ pcci,
                       float* __restrict__ pccc,
                       int* __restrict__ zerobase, int nzero,
                       int Z, int C, int Wb, int N) {
    const int bid = blockIdx.x;
    const int tid = threadIdx.x;
    if (bid < Z) {                                   // zero-init region
        int i = bid * 256 + tid;
        if (i < nzero) zerobase[i] = 0;
        return;
    }
    if (bid < Z + C) {                               // x -> f16
        size_t i = (size_t)(bid - Z) * 256 + tid;    // i indexes float4 groups
        if (i >= (size_t)N * 32) return;
        float4 v = *(const float4*)(x + i * 4);
        union { uint2 u; _Float16 h[4]; } o;
        o.h[0] = (_Float16)v.x; o.h[1] = (_Float16)v.y;
        o.h[2] = (_Float16)v.z; o.h[3] = (_Float16)v.w;
        *(uint2*)(x16 + i * 4) = o.u;
        return;
    }
    if (bid < Z + C + Wb) {                          // wcat panels [552][256][8] x3 layers
        size_t t = (size_t)(bid - Z - C) * 256 + tid;
        const size_t PL = 552u * 256u * 8u;
        int l = (int)(t / PL);
        size_t rem = t - (size_t)l * PL;
        int kp = (int)(rem >> 11);
        int o = (int)((rem >> 3) & 255);
        int e = (int)(rem & 7);
        int k = kp * 8 + e;
        float v;
        if (k < 4096)      v = Wr[((((size_t)l * 16 + (k >> 8)) * 256) + (k & 255)) * 256 + o];
        else if (k < 4352) v = Ws[(((size_t)l * 256) + (k - 4096)) * 256 + o];
        else if (k < 4368) v = br[(((size_t)l * 16) + (k - 4352)) * 256 + o];
        else               v = 0.f;
        union { u16 u; _Float16 h; } c; c.h = (_Float16)v;
        wcat[t] = c.u;
        return;
    }
    if (bid < Z + C + Wb + 128) {                    // panelize W_in (K=128,M=256)
        size_t t = (size_t)(bid - Z - C - Wb) * 256 + tid;
        int e = (int)(t & 7), o = (int)((t >> 3) & 255);
        int kp = (int)(t >> 11);
        union { u16 u; _Float16 h; } c; c.h = (_Float16)W_in[(size_t)(kp * 8 + e) * 256 + o];
        winp[t] = c.u;
        return;
    }
    if (bid < Z + C + Wb + 256) {                    // panelize W_h1 (K=256,M=128)
        size_t t = (size_t)(bid - Z - C - Wb - 128) * 256 + tid;
        int e = (int)(t & 7), o = (int)((t >> 3) & 127);
        int kp = (int)(t >> 10);
        union { u16 u; _Float16 h; } c; c.h = (_Float16)W_h1[(size_t)(kp * 8 + e) * 128 + o];
        wh1p[t] = c.u;
        return;
    }
    {                                                // pc_build: 48 blocks
        int lr = bid - (Z + C + Wb + 256);
        size_t idx = (size_t)lr * 256 + tid;
        float ls = logsig[idx];
        float inv = expf(-2.f * ls);
        float c = centers[idx];
        pcinv[idx] = inv;
        pcci[idx] = c * inv;
        __shared__ float sm[256];
        sm[tid] = c * c * inv;
        __syncthreads();
        for (int s = 128; s > 0; s >>= 1) { if (tid < s) sm[tid] += sm[tid + s]; __syncthreads(); }
        if (tid == 0) pccc[lr] = sm[0];
    }
}

// ===========================================================================
// Gated CSR build: runs only if (bany[l] && !csr_done). agg_k sets csr_done.
// ===========================================================================

__global__ void deg_count_g(const int* __restrict__ dst, int* __restrict__ deg,
                            const int* __restrict__ bany, const int* __restrict__ done, int E) {
    if (*bany == 0 || *done != 0) return;
    int e = blockIdx.x * 256 + threadIdx.x;
    if (e < E) atomicAdd(&deg[dst[e]], 1);
}

__global__ void csr_scan_g(const int* __restrict__ deg, int* __restrict__ indptr,
                           int* __restrict__ cursor, float* __restrict__ deginv,
                           const int* __restrict__ bany, const int* __restrict__ done, int n) {
    if (*bany == 0 || *done != 0) return;
    const int tid = threadIdx.x;   // 1024 threads, 1 block (cold path only)
    const int chunk = (n + 1023) >> 10;
    int s0 = tid * chunk, s1 = s0 + chunk; if (s1 > n) s1 = n; if (s0 > n) s0 = n;
    int tot = 0;
    for (int i = s0; i < s1; ++i) tot += deg[i];
    __shared__ int sm[1024];
    sm[tid] = tot; __syncthreads();
    for (int off = 1; off < 1024; off <<= 1) {
        int t = (tid >= off) ? sm[tid - off] : 0;
        __syncthreads(); sm[tid] += t; __syncthreads();
    }
    int base = sm[tid] - tot;
    for (int i = s0; i < s1; ++i) {
        int d = deg[i];
        indptr[i] = base; cursor[i] = base;
        deginv[i] = 1.f / (float)(d > 1 ? d : 1);
        base += d;
    }
    if (tid == 1023) indptr[n] = sm[1023];
}

__global__ void edge_scatter_g(const int* __restrict__ src, const int* __restrict__ dst,
                               int* __restrict__ cursor, int* __restrict__ ssrc,
                               const int* __restrict__ bany, const int* __restrict__ done, int E) {
    if (*bany == 0 || *done != 0) return;
    int e = blockIdx.x * 256 + threadIdx.x;
    if (e < E) {
        int d = dst[e];
        int pos = atomicAdd(&cursor[d], 1);
        ssrc[pos] = src[e];
    }
}

// ===========================================================================
// Membership for layer 0 (reads f32 h). mu[n,r]; sets bflag[node>>7], bany=[511].
// ===========================================================================

__device__ __forceinline__ void membership_body(float h0, float h1, float h2, float h3,
                                                int lane, int node,
                                                const float* __restrict__ pcinv,
                                                const float* __restrict__ pcci,
                                                const float* __restrict__ pccc,
                                                u16* __restrict__ mu16, int* __restrict__ bflag) {
    int c = lane * 4;
    float f[16]; float s = 0.f;
#pragma unroll
    for (int r = 0; r < 16; ++r) {
        float4 inv = *(const float4*)(pcinv + r * 256 + c);
        float4 ci  = *(const float4*)(pcci + r * 256 + c);
        float t = h0 * (h0 * inv.x - 2.f * ci.x) + h1 * (h1 * inv.y - 2.f * ci.y)
                + h2 * (h2 * inv.z - 2.f * ci.z) + h3 * (h3 * inv.w - 2.f * ci.w);
#pragma unroll
        for (int off = 32; off; off >>= 1) t += __shfl_xor(t, off);
        float d = t + pccc[r];
        float fr = expf(-0.5f * d);
        f[r] = fr; s += fr;
    }
    float is = 1.f / (s + 1e-12f);
    if (lane < 16) {
        union { u16 u; _Float16 h; } c2; c2.h = (_Float16)(f[lane] * is);
        mu16[(size_t)node * 16 + lane] = c2.u;
    }
    if (lane == 0 && s > 0.f) {
        atomicOr(&bflag[node >> 7], 1);
        atomicOr(&bflag[511], 1);
    }
}

__global__ void membership_k(const float* __restrict__ h,
                             const float* __restrict__ pcinv, const float* __restrict__ pcci,
                             const float* __restrict__ pccc,
                             u16* __restrict__ mu16, int* __restrict__ bflag, int n) {
    int lane = threadIdx.x & 63, wave = threadIdx.x >> 6;
    int node = blockIdx.x * 4 + wave;
    if (node >= n) return;
    float4 hv = *(const float4*)(h + (size_t)node * 256 + lane * 4);
    membership_body(hv.x, hv.y, hv.z, hv.w, lane, node, pcinv, pcci, pccc, mu16, bflag);
}

// ===========================================================================
// Neighbor mean (grid-stride; early-exits unless this layer fired). Also sets
// csr_done after a build (safe: scatter completed in a previous dispatch).
// ===========================================================================

__global__ void agg_k(const u16* __restrict__ h16, const int* __restrict__ indptr,
                      const int* __restrict__ ssrc, const float* __restrict__ deginv,
                      const int* __restrict__ bflag, int* __restrict__ done,
                      u16* __restrict__ agg16, int n) {
    if (bflag[511] == 0) return;
    if (blockIdx.x == 0 && threadIdx.x == 0 && *done == 0) *done = 1;
    int lane = threadIdx.x & 63, wave = threadIdx.x >> 6;
    for (int node = blockIdx.x * 4 + wave; node < n; node += gridDim.x * 4) {
        if (bflag[node >> 7] == 0) continue;
        int j0 = indptr[node], j1 = indptr[node + 1];
        float a0 = 0, a1 = 0, a2 = 0, a3 = 0;
        for (int j = j0; j < j1; ++j) {
            int sN = ssrc[j];
            union { uint2 u; _Float16 h[4]; } hv;
            hv.u = *(const uint2*)(h16 + (size_t)sN * 256 + lane * 4);
            a0 += (float)hv.h[0]; a1 += (float)hv.h[1];
            a2 += (float)hv.h[2]; a3 += (float)hv.h[3];
        }
        float di = deginv[node];
        union { uint2 u; _Float16 h[4]; } o;
        o.h[0] = (_Float16)(a0 * di); o.h[1] = (_Float16)(a1 * di);
        o.h[2] = (_Float16)(a2 * di); o.h[3] = (_Float16)(a3 * di);
        *(uint2*)(agg16 + (size_t)node * 256 + lane * 4) = o.u;
    }
}

// ===========================================================================
// Unified f16 MFMA GEMM. 128x128 tile, BK=64, 256 threads (4 waves).
// MODE 0: h = relu(x16 @ Winp + b_in)   (K=128)  -> h f32 + h16
// MODE 1: pre16 = [mu*agg | h | mu]@Wcat + b_self (fuzzy K skipped if !bflag)
// MODE 2: q16 = relu(h16 @ Wh1p + b_h1) (K=256)
// ===========================================================================

template <int MODE, int NCHUNK>
__launch_bounds__(256, 2)
__global__ void gemm_k(const u16* __restrict__ A, const u16* __restrict__ A2,
                       const u16* __restrict__ MU, const u16* __restrict__ Bp,
                       const float* __restrict__ bias, const int* __restrict__ bflag,
                       float* __restrict__ outF, u16* __restrict__ outH,
                       int nrows, int mcols, int astride) {
    __shared__ __align__(16) u16 lA[8192];
    __shared__ __align__(16) u16 lB[8192];
    const int tid = threadIdx.x;
    const int row0 = blockIdx.x * 128;
    const int c0 = blockIdx.y * 128;
    const int lane = tid & 63;
    const int q = lane >> 4, mm = lane & 15;
    const int wave = tid >> 6;
    const int wm = wave >> 1, wn = wave & 1;

    f32x4 acc[4][4];
#pragma unroll
    for (int i = 0; i < 4; ++i)
#pragma unroll
        for (int j = 0; j < 4; ++j) acc[i][j] = (f32x4){0.f, 0.f, 0.f, 0.f};

    int cb = 0, cbEnd = NCHUNK;
    if (MODE == 1 && bflag[blockIdx.x] == 0) { cb = 64; cbEnd = 68; }  // mu==0: fuzzy+mu K exact-zero

    for (; cb < cbEnd; ++cb) {
#pragma unroll
        for (int it = 0; it < 4; ++it) {
            int idx = it * 256 + tid;
            int p = idx >> 7, col = idx & 127;
            uint4 v = *(const uint4*)(Bp + (((size_t)(cb * 8 + p)) * mcols + c0 + col) * 8);
            *(uint4*)(lB + (size_t)idx * 8) = v;
        }
#pragma unroll
        for (int it = 0; it < 4; ++it) {
            int idx = it * 256 + tid;
            int p = idx >> 7, row = idx & 127;
            int grow = row0 + row; if (grow >= nrows) grow = nrows - 1;
            uint4 v;
            if (MODE != 1) {
                v = *(const uint4*)(A + (size_t)grow * astride + cb * 64 + p * 8);
            } else {
                if (cb < 64) {
                    int r = cb >> 2;
                    int i0 = ((cb & 3) << 6) + (p << 3);
                    v = *(const uint4*)(A + (size_t)grow * 256 + i0);
                    union { u16 u; _Float16 h; } mu; mu.u = MU[(size_t)grow * 16 + r];
                    union { uint4 u4; _Float16 h[8]; } wv; wv.u4 = v;
#pragma unroll
                    for (int j = 0; j < 8; ++j) wv.h[j] = wv.h[j] * mu.h;
                    v = wv.u4;
                } else if (cb < 68) {
                    int i0 = ((cb - 64) << 6) + (p << 3);
                    v = *(const uint4*)(A2 + (size_t)grow * 256 + i0);
                } else {
                    int j0 = p << 3;
                    if (j0 < 16) v = *(const uint4*)(MU + (size_t)grow * 16 + j0);
                    else v = (uint4){0, 0, 0, 0};
                }
            }
            *(uint4*)(lA + (size_t)idx * 8) = v;
        }
        __syncthreads();
#pragma unroll
        for (int kc = 0; kc < 2; ++kc) {
            int pp = kc * 4 + q;
            half8 af[4], bf[4];
#pragma unroll
            for (int mt = 0; mt < 4; ++mt)
                af[mt] = *(const half8*)(lA + ((size_t)pp * 128 + wm * 64 + mt * 16 + mm) * 8);
#pragma unroll
            for (int nt = 0; nt < 4; ++nt)
                bf[nt] = *(const half8*)(lB + ((size_t)pp * 128 + wn * 64 + nt * 16 + mm) * 8);
#pragma unroll
            for (int mt = 0; mt < 4; ++mt)
#pragma unroll
                for (int nt = 0; nt < 4; ++nt)
                    acc[mt][nt] = __builtin_amdgcn_mfma_f32_16x16x32_f16(af[mt], bf[nt], acc[mt][nt], 0, 0, 0);
        }
        __syncthreads();
    }

    // epilogue: C/D layout col=lane&15, row=q*4+reg
#pragma unroll
    for (int mt = 0; mt < 4; ++mt) {
#pragma unroll
        for (int nt = 0; nt < 4; ++nt) {
#pragma unroll
            for (int r = 0; r < 4; ++r) {
                int grow = row0 + wm * 64 + mt * 16 + q * 4 + r;
                int gcol = c0 + wn * 64 + nt * 16 + mm;
                if (grow < nrows) {
                    float v = acc[mt][nt][r] + bias[gcol];
                    if (MODE == 0) {
                        v = fmaxf(v, 0.f);
                        outF[(size_t)grow * mcols + gcol] = v;
                        union { u16 u; _Float16 h; } cc; cc.h = (_Float16)v;
                        outH[(size_t)grow * mcols + gcol] = cc.u;
                    } else if (MODE == 1) {
                        union { u16 u; _Float16 h; } cc; cc.h = (_Float16)v;
                        outH[(size_t)grow * mcols + gcol] = cc.u;
                    } else {
                        v = fmaxf(v, 0.f);
                        union { u16 u; _Float16 h; } cc; cc.h = (_Float16)v;
                        outH[(size_t)grow * mcols + gcol] = cc.u;
                    }
                }
            }
        }
    }
}

// ===========================================================================
// BN stats over pre16 + last-block finalize into ab[] (alpha/shift).
// area: 512 floats of sums + int counter at [512].
// ===========================================================================

__global__ void bn_k(const u16* __restrict__ pre16, float* __restrict__ area,
                     const float* __restrict__ gamma, const float* __restrict__ beta,
                     float* __restrict__ ab, int n, int nblocks) {
    const int t = threadIdx.x;
    const int cp = t & 127, half = t >> 7;
    int r0 = blockIdx.x * 512 + half;
    int r1 = blockIdx.x * 512 + 512; if (r1 > n) r1 = n;
    float s0 = 0, s1 = 0, q0 = 0, q1 = 0;
    for (int r = r0; r < r1; r += 2) {
        union { u32 u; _Float16 h[2]; } v;
        v.u = *(const u32*)(pre16 + (size_t)r * 256 + cp * 2);
        float a = (float)v.h[0], b = (float)v.h[1];
        s0 += a; s1 += b; q0 += a * a; q1 += b * b;
    }
    atomicAdd(&area[cp * 2], s0);
    atomicAdd(&area[cp * 2 + 1], s1);
    atomicAdd(&area[256 + cp * 2], q0);
    atomicAdd(&area[256 + cp * 2 + 1], q1);
    __threadfence();
    __shared__ int lastf;
    if (t == 0) {
        int old = atomicAdd((int*)(area + 512), 1);
        lastf = (old == nblocks - 1);
    }
    __syncthreads();
    if (!lastf) return;
    int col = t;
    float s = atomicAdd(&area[col], 0.f);
    float ss = atomicAdd(&area[256 + col], 0.f);
    float mean = s / (float)n;
    float var = ss / (float)n - mean * mean;
    float al = gamma[col] * rsqrtf(var + 1e-5f);
    ab[col] = al;
    ab[256 + col] = beta[col] - mean * al;
}

// ===========================================================================
// Fused residual update (+ membership for next layer when DOMEMB).
// h += relu(pre*alpha + shift); h16 updated; membership from f32 registers.
// ===========================================================================

template <int DOMEMB>
__global__ void update_k(const u16* __restrict__ pre16, const float* __restrict__ ab,
                         float* __restrict__ h, u16* __restrict__ h16,
                         const float* __restrict__ pcinv, const float* __restrict__ pcci,
                         const float* __restrict__ pccc,
                         u16* __restrict__ mu16, int* __restrict__ bflag, int n) {
    int lane = threadIdx.x & 63, wave = threadIdx.x >> 6;
    int node = blockIdx.x * 4 + wave;
    if (node >= n) return;
    int c = lane * 4;
    size_t base = (size_t)node * 256 + c;
    union { uint2 u; _Float16 hh[4]; } p; p.u = *(const uint2*)(pre16 + base);
    float4 al = *(const float4*)(ab + c);
    float4 sh = *(const float4*)(ab + 256 + c);
    float4 hv = *(const float4*)(h + base);
    float v0 = hv.x + fmaxf((float)p.hh[0] * al.x + sh.x, 0.f);
    float v1 = hv.y + fmaxf((float)p.hh[1] * al.y + sh.y, 0.f);
    float v2 = hv.z + fmaxf((float)p.hh[2] * al.z + sh.z, 0.f);
    float v3 = hv.w + fmaxf((float)p.hh[3] * al.w + sh.w, 0.f);
    *(float4*)(h + base) = (float4){v0, v1, v2, v3};
    union { uint2 u; _Float16 hh[4]; } o;
    o.hh[0] = (_Float16)v0; o.hh[1] = (_Float16)v1;
    o.hh[2] = (_Float16)v2; o.hh[3] = (_Float16)v3;
    *(uint2*)(h16 + base) = o.u;
    if (DOMEMB)
        membership_body(v0, v1, v2, v3, lane, node, pcinv, pcci, pccc, mu16, bflag);
}

// ===========================================================================
// Head: logits = q16 @ W_h2 + b_h2, softmax. One thread per node, W_h2 in LDS.
// ===========================================================================

__launch_bounds__(256)
__global__ void head_k(const u16* __restrict__ q16, const float* __restrict__ Wh2,
                       const float* __restrict__ bh2, float* __restrict__ out, int n) {
    __shared__ float W[5160];
    for (int i = threadIdx.x; i < 5160; i += 256)
        W[i] = (i < 5120) ? Wh2[i] : bh2[i - 5120];
    __syncthreads();
    int node = blockIdx.x * 256 + threadIdx.x;
    if (node >= n) return;
    float acc[40];
#pragma unroll
    for (int o = 0; o < 40; ++o) acc[o] = W[5120 + o];
    const u32* qp = (const u32*)(q16 + (size_t)node * 128);
    for (int k2 = 0; k2 < 64; ++k2) {
        union { u32 u; _Float16 h[2]; } qq; qq.u = qp[k2];
        float a = (float)qq.h[0], b = (float)qq.h[1];
        const float* w0 = W + (k2 * 2) * 40;
        const float* w1 = w0 + 40;
#pragma unroll
        for (int o = 0; o < 40; ++o) acc[o] += a * w0[o] + b * w1[o];
    }
    float mx = acc[0];
#pragma unroll
    for (int o = 1; o < 40; ++o) mx = fmaxf(mx, acc[o]);
    float s = 0.f;
#pragma unroll
    for (int o = 0; o < 40; ++o) { float e = expf(acc[o] - mx); acc[o] = e; s += e; }
    float is = 1.f / s;
    float* op = out + (size_t)node * 40;
#pragma unroll
    for (int o = 0; o < 40; ++o) op[o] = acc[o] * is;
}

// ===========================================================================
// Launch
// ===========================================================================

extern "C" void kernel_launch(void* const* d_in, const int* in_sizes, int n_in,
                              void* d_out, int out_size, void* d_ws, size_t ws_size,
                              hipStream_t stream) {
    const float* x       = (const float*)d_in[0];
    const int*   ei      = (const int*)d_in[1];
    const float* W_in    = (const float*)d_in[2];
    const float* b_in    = (const float*)d_in[3];
    const float* centers = (const float*)d_in[4];
    const float* logsig  = (const float*)d_in[5];
    const float* W_rule  = (const float*)d_in[6];
    const float* b_rule  = (const float*)d_in[7];
    const float* W_self  = (const float*)d_in[8];
    const float* b_self  = (const float*)d_in[9];
    const float* gamma   = (const float*)d_in[10];
    const float* beta    = (const float*)d_in[11];
    const float* W_h1    = (const float*)d_in[12];
    const float* b_h1    = (const float*)d_in[13];
    const float* W_h2    = (const float*)d_in[14];
    const float* b_h2    = (const float*)d_in[15];

    const int N = in_sizes[0] / 128;
    const int E = in_sizes[1] / 2;
    const int* e_src = ei;
    const int* e_dst = ei + E;

    char* w = (char*)d_ws;
    size_t off = 0;
    auto alloc = [&](size_t bytes) -> void* {
        void* p = w + off;
        off = (off + bytes + 255) & ~(size_t)255;
        return p;
    };

    u16*   x16    = (u16*)  alloc((size_t)N * 128 * 2);
    float* h      = (float*)alloc((size_t)N * 256 * 4);
    u16*   h16    = (u16*)  alloc((size_t)N * 256 * 2);
    u16*   pre16  = (u16*)  alloc((size_t)N * 256 * 2);
    u16*   agg16  = (u16*)  alloc((size_t)N * 256 * 2);
    u16*   mu16   = (u16*)  alloc((size_t)N * 16 * 2);
    u16*   q16    = (u16*)  alloc((size_t)N * 128 * 2);
    u16*   wcat   = (u16*)  alloc((size_t)3 * 552 * 256 * 8 * 2);
    u16*   winp   = (u16*)  alloc((size_t)16 * 256 * 8 * 2);
    u16*   wh1p   = (u16*)  alloc((size_t)32 * 128 * 8 * 2);
    float* pcinv  = (float*)alloc((size_t)48 * 256 * 4);
    float* pcci   = (float*)alloc((size_t)48 * 256 * 4);
    float* pccc   = (float*)alloc((size_t)48 * 4);
    int*   indptr = (int*)  alloc((size_t)(N + 1) * 4);
    int*   cursor = (int*)  alloc((size_t)N * 4);
    float* deginv = (float*)alloc((size_t)N * 4);
    int*   ssrc   = (int*)  alloc((size_t)E * 4);
    float* bnab   = (float*)alloc((size_t)3 * 512 * 4);
    // zero region: [deg N][bflag 3*512][bnarea 3*768 floats][csr_done]
    const int nzero = N + 3 * 512 + 3 * 768 + 64;
    int*   zerob  = (int*)  alloc((size_t)nzero * 4);
    int*   deg    = zerob;
    int*   bflagA = zerob + N;
    float* bnarea = (float*)(zerob + N + 3 * 512);
    int*   done   = zerob + N + 3 * 512 + 3 * 768;

    const int Z = cdiv(nzero, 256);
    const int C = cdiv(N * 32, 256);
    const int Wb = 3 * 552 * 256 * 8 / 256;   // 13248
    const int prep_grid = Z + C + Wb + 128 + 128 + 48;
    const int gx = cdiv(N, 128);

    prep_k<<<prep_grid, 256, 0, stream>>>(x, W_rule, W_self, b_rule, W_in, W_h1,
                                          centers, logsig, x16, wcat, winp, wh1p,
                                          pcinv, pcci, pccc, zerob, nzero, Z, C, Wb, N);

    gemm_k<0, 2><<<dim3(gx, 2), 256, 0, stream>>>(x16, nullptr, nullptr, winp, b_in,
                                                  nullptr, h, h16, N, 256, 128);
    membership_k<<<cdiv(N, 4), 256, 0, stream>>>(h, pcinv, pcci, pccc, mu16, bflagA, N);

    for (int l = 0; l < 3; ++l) {
        int* bf = bflagA + l * 512;
        int* bany = bf + 511;
        deg_count_g<<<cdiv(E, 256), 256, 0, stream>>>(e_dst, deg, bany, done, E);
        csr_scan_g<<<1, 1024, 0, stream>>>(deg, indptr, cursor, deginv, bany, done, N);
        edge_scatter_g<<<cdiv(E, 256), 256, 0, stream>>>(e_src, e_dst, cursor, ssrc, bany, done, E);
        agg_k<<<1024, 256, 0, stream>>>(h16, indptr, ssrc, deginv, bf, done, agg16, N);
        gemm_k<1, 69><<<dim3(gx, 2), 256, 0, stream>>>(agg16, h16, mu16,
                                                       wcat + (size_t)l * 552 * 256 * 8,
                                                       b_self + l * 256, bf, nullptr, pre16,
                                                       N, 256, 0);
        bn_k<<<cdiv(N, 512), 256, 0, stream>>>(pre16, bnarea + l * 768, gamma + l * 256,
                                               beta + l * 256, bnab + l * 512, N, cdiv(N, 512));
        if (l < 2) {
            update_k<1><<<cdiv(N, 4), 256, 0, stream>>>(pre16, bnab + l * 512, h, h16,
                                                        pcinv + (size_t)(l + 1) * 16 * 256,
                                                        pcci + (size_t)(l + 1) * 16 * 256,
                                                        pccc + (l + 1) * 16, mu16,
                                                        bflagA + (l + 1) * 512, N);
        } else {
            update_k<0><<<cdiv(N, 4), 256, 0, stream>>>(pre16, bnab + l * 512, h, h16,
                                                        nullptr, nullptr, nullptr,
                                                        nullptr, nullptr, N);
        }
    }

    gemm_k<2, 4><<<dim3(gx, 1), 256, 0, stream>>>(h16, nullptr, nullptr, wh1p, b_h1,
                                                  nullptr, nullptr, q16, N, 128, 256);
    head_k<<<cdiv(N, 256), 256, 0, stream>>>(q16, W_h2, b_h2, (float*)d_out, N);
}

// Round 3
// 595.189 us; speedup vs baseline: 2.0009x; 1.2661x over previous
//
#include <hip/hip_runtime.h>
#include <hip/hip_fp16.h>
#include <cstdint>
#include <cstddef>

using u16 = unsigned short;
using u32 = unsigned int;

typedef _Float16 half8 __attribute__((ext_vector_type(8)));
typedef float f32x4 __attribute__((ext_vector_type(4)));

static inline int cdiv(int a, int b) { return (a + b - 1) / b; }

// ===========================================================================
// prep_k: fused zero-init + f16 cast + weight panelization + rule precompute.
// ===========================================================================

__global__ void prep_k(const float* __restrict__ x, const float* __restrict__ Wr,
                       const float* __restrict__ Ws, const float* __restrict__ br,
                       const float* __restrict__ W_in, const float* __restrict__ W_h1,
                       const float* __restrict__ centers, const float* __restrict__ logsig,
                       u16* __restrict__ x16, u16* __restrict__ wcat,
                       u16* __restrict__ winp, u16* __restrict__ wh1p,
                       float* __restrict__ pcinv, float* __restrict__ pcci,
                       float* __restrict__ pccc,
                       int* __restrict__ zerobase, int nzero,
                       int Z, int C, int Wb, int N) {
    const int bid = blockIdx.x;
    const int tid = threadIdx.x;
    if (bid < Z) {                                   // zero-init region
        int i = bid * 256 + tid;
        if (i < nzero) zerobase[i] = 0;
        return;
    }
    if (bid < Z + C) {                               // x -> f16
        size_t i = (size_t)(bid - Z) * 256 + tid;
        if (i >= (size_t)N * 32) return;
        float4 v = *(const float4*)(x + i * 4);
        union { uint2 u; _Float16 h[4]; } o;
        o.h[0] = (_Float16)v.x; o.h[1] = (_Float16)v.y;
        o.h[2] = (_Float16)v.z; o.h[3] = (_Float16)v.w;
        *(uint2*)(x16 + i * 4) = o.u;
        return;
    }
    if (bid < Z + C + Wb) {                          // wcat panels [552][256][8] x3 layers
        size_t t = (size_t)(bid - Z - C) * 256 + tid;
        const size_t PL = 552u * 256u * 8u;
        int l = (int)(t / PL);
        size_t rem = t - (size_t)l * PL;
        int kp = (int)(rem >> 11);
        int o = (int)((rem >> 3) & 255);
        int e = (int)(rem & 7);
        int k = kp * 8 + e;
        float v;
        if (k < 4096)      v = Wr[((((size_t)l * 16 + (k >> 8)) * 256) + (k & 255)) * 256 + o];
        else if (k < 4352) v = Ws[(((size_t)l * 256) + (k - 4096)) * 256 + o];
        else if (k < 4368) v = br[(((size_t)l * 16) + (k - 4352)) * 256 + o];
        else               v = 0.f;
        union { u16 u; _Float16 h; } c; c.h = (_Float16)v;
        wcat[t] = c.u;
        return;
    }
    if (bid < Z + C + Wb + 128) {                    // panelize W_in (K=128,M=256)
        size_t t = (size_t)(bid - Z - C - Wb) * 256 + tid;
        int e = (int)(t & 7), o = (int)((t >> 3) & 255);
        int kp = (int)(t >> 11);
        union { u16 u; _Float16 h; } c; c.h = (_Float16)W_in[(size_t)(kp * 8 + e) * 256 + o];
        winp[t] = c.u;
        return;
    }
    if (bid < Z + C + Wb + 256) {                    // panelize W_h1 (K=256,M=128)
        size_t t = (size_t)(bid - Z - C - Wb - 128) * 256 + tid;
        int e = (int)(t & 7), o = (int)((t >> 3) & 127);
        int kp = (int)(t >> 10);
        union { u16 u; _Float16 h; } c; c.h = (_Float16)W_h1[(size_t)(kp * 8 + e) * 128 + o];
        wh1p[t] = c.u;
        return;
    }
    {                                                // pc_build: 48 blocks
        int lr = bid - (Z + C + Wb + 256);
        size_t idx = (size_t)lr * 256 + tid;
        float ls = logsig[idx];
        float inv = expf(-2.f * ls);
        float c = centers[idx];
        pcinv[idx] = inv;
        pcci[idx] = c * inv;
        __shared__ float sm[256];
        sm[tid] = c * c * inv;
        __syncthreads();
        for (int s = 128; s > 0; s >>= 1) { if (tid < s) sm[tid] += sm[tid + s]; __syncthreads(); }
        if (tid == 0) pccc[lr] = sm[0];
    }
}

// ===========================================================================
// Gated CSR build: runs only if (bany[l] && !csr_done). agg_k sets csr_done.
// ===========================================================================

__global__ void deg_count_g(const int* __restrict__ dst, int* __restrict__ deg,
                            const int* __restrict__ bany, const int* __restrict__ done, int E) {
    if (*bany == 0 || *done != 0) return;
    int e = blockIdx.x * 256 + threadIdx.x;
    if (e < E) atomicAdd(&deg[dst[e]], 1);
}

__global__ void csr_scan_g(const int* __restrict__ deg, int* __restrict__ indptr,
                           int* __restrict__ cursor, float* __restrict__ deginv,
                           const int* __restrict__ bany, const int* __restrict__ done, int n) {
    if (*bany == 0 || *done != 0) return;
    const int tid = threadIdx.x;   // 1024 threads, 1 block (cold path only)
    const int chunk = (n + 1023) >> 10;
    int s0 = tid * chunk, s1 = s0 + chunk; if (s1 > n) s1 = n; if (s0 > n) s0 = n;
    int tot = 0;
    for (int i = s0; i < s1; ++i) tot += deg[i];
    __shared__ int sm[1024];
    sm[tid] = tot; __syncthreads();
    for (int off = 1; off < 1024; off <<= 1) {
        int t = (tid >= off) ? sm[tid - off] : 0;
        __syncthreads(); sm[tid] += t; __syncthreads();
    }
    int base = sm[tid] - tot;
    for (int i = s0; i < s1; ++i) {
        int d = deg[i];
        indptr[i] = base; cursor[i] = base;
        deginv[i] = 1.f / (float)(d > 1 ? d : 1);
        base += d;
    }
    if (tid == 1023) indptr[n] = sm[1023];
}

__global__ void edge_scatter_g(const int* __restrict__ src, const int* __restrict__ dst,
                               int* __restrict__ cursor, int* __restrict__ ssrc,
                               const int* __restrict__ bany, const int* __restrict__ done, int E) {
    if (*bany == 0 || *done != 0) return;
    int e = blockIdx.x * 256 + threadIdx.x;
    if (e < E) {
        int d = dst[e];
        int pos = atomicAdd(&cursor[d], 1);
        ssrc[pos] = src[e];
    }
}

// ===========================================================================
// Membership. mu[n,r]; sets bflag[node>>7], bany=[511].
// ===========================================================================

__device__ __forceinline__ void membership_body(float h0, float h1, float h2, float h3,
                                                int lane, int node,
                                                const float* __restrict__ pcinv,
                                                const float* __restrict__ pcci,
                                                const float* __restrict__ pccc,
                                                u16* __restrict__ mu16, int* __restrict__ bflag) {
    int c = lane * 4;
    float f[16]; float s = 0.f;
#pragma unroll
    for (int r = 0; r < 16; ++r) {
        float4 inv = *(const float4*)(pcinv + r * 256 + c);
        float4 ci  = *(const float4*)(pcci + r * 256 + c);
        float t = h0 * (h0 * inv.x - 2.f * ci.x) + h1 * (h1 * inv.y - 2.f * ci.y)
                + h2 * (h2 * inv.z - 2.f * ci.z) + h3 * (h3 * inv.w - 2.f * ci.w);
#pragma unroll
        for (int off = 32; off; off >>= 1) t += __shfl_xor(t, off);
        float d = t + pccc[r];
        float fr = expf(-0.5f * d);
        f[r] = fr; s += fr;
    }
    float is = 1.f / (s + 1e-12f);
    if (lane < 16) {
        union { u16 u; _Float16 h; } c2; c2.h = (_Float16)(f[lane] * is);
        mu16[(size_t)node * 16 + lane] = c2.u;
    }
    if (lane == 0 && s > 0.f) {
        atomicOr(&bflag[node >> 7], 1);
        atomicOr(&bflag[511], 1);
    }
}

__global__ void membership_k(const u16* __restrict__ h16,
                             const float* __restrict__ pcinv, const float* __restrict__ pcci,
                             const float* __restrict__ pccc,
                             u16* __restrict__ mu16, int* __restrict__ bflag, int n) {
    int lane = threadIdx.x & 63, wave = threadIdx.x >> 6;
    int node = blockIdx.x * 4 + wave;
    if (node >= n) return;
    union { uint2 u; _Float16 h[4]; } hv;
    hv.u = *(const uint2*)(h16 + (size_t)node * 256 + lane * 4);
    membership_body((float)hv.h[0], (float)hv.h[1], (float)hv.h[2], (float)hv.h[3],
                    lane, node, pcinv, pcci, pccc, mu16, bflag);
}

// ===========================================================================
// Neighbor mean (grid-stride; early-exits unless this layer fired).
// ===========================================================================

__global__ void agg_k(const u16* __restrict__ h16, const int* __restrict__ indptr,
                      const int* __restrict__ ssrc, const float* __restrict__ deginv,
                      const int* __restrict__ bflag, int* __restrict__ done,
                      u16* __restrict__ agg16, int n) {
    if (bflag[511] == 0) return;
    if (blockIdx.x == 0 && threadIdx.x == 0 && *done == 0) *done = 1;
    int lane = threadIdx.x & 63, wave = threadIdx.x >> 6;
    for (int node = blockIdx.x * 4 + wave; node < n; node += gridDim.x * 4) {
        if (bflag[node >> 7] == 0) continue;
        int j0 = indptr[node], j1 = indptr[node + 1];
        float a0 = 0, a1 = 0, a2 = 0, a3 = 0;
        for (int j = j0; j < j1; ++j) {
            int sN = ssrc[j];
            union { uint2 u; _Float16 h[4]; } hv;
            hv.u = *(const uint2*)(h16 + (size_t)sN * 256 + lane * 4);
            a0 += (float)hv.h[0]; a1 += (float)hv.h[1];
            a2 += (float)hv.h[2]; a3 += (float)hv.h[3];
        }
        float di = deginv[node];
        union { uint2 u; _Float16 h[4]; } o;
        o.h[0] = (_Float16)(a0 * di); o.h[1] = (_Float16)(a1 * di);
        o.h[2] = (_Float16)(a2 * di); o.h[3] = (_Float16)(a3 * di);
        *(uint2*)(agg16 + (size_t)node * 256 + lane * 4) = o.u;
    }
}

// ===========================================================================
// Unified f16 MFMA GEMM. 128x128 tile, BK=64, 256 threads (4 waves).
// MODE 0: h = relu(x16 @ Winp + b_in)   (K=128)  -> h f32 + h16
// MODE 1: pre16 = [mu*agg | h | mu]@Wcat + b_self; BN stats fused via atomics.
// MODE 2: q16 = relu(h16 @ Wh1p + b_h1) (K=256)
// ===========================================================================

template <int MODE, int NCHUNK>
__launch_bounds__(256, 2)
__global__ void gemm_k(const u16* __restrict__ A, const u16* __restrict__ A2,
                       const u16* __restrict__ MU, const u16* __restrict__ Bp,
                       const float* __restrict__ bias, const int* __restrict__ bflag,
                       float* __restrict__ outF, u16* __restrict__ outH,
                       float* __restrict__ bnsum,
                       int nrows, int mcols, int astride) {
    __shared__ __align__(16) u16 lA[8192];
    __shared__ __align__(16) u16 lB[8192];
    const int tid = threadIdx.x;
    const int row0 = blockIdx.x * 128;
    const int c0 = blockIdx.y * 128;
    const int lane = tid & 63;
    const int q = lane >> 4, mm = lane & 15;
    const int wave = tid >> 6;
    const int wm = wave >> 1, wn = wave & 1;

    f32x4 acc[4][4];
#pragma unroll
    for (int i = 0; i < 4; ++i)
#pragma unroll
        for (int j = 0; j < 4; ++j) acc[i][j] = (f32x4){0.f, 0.f, 0.f, 0.f};

    int cb = 0, cbEnd = NCHUNK;
    if (MODE == 1 && bflag[blockIdx.x] == 0) { cb = 64; cbEnd = 68; }  // mu==0: fuzzy+mu K exact-zero

    for (; cb < cbEnd; ++cb) {
#pragma unroll
        for (int it = 0; it < 4; ++it) {
            int idx = it * 256 + tid;
            int p = idx >> 7, col = idx & 127;
            uint4 v = *(const uint4*)(Bp + (((size_t)(cb * 8 + p)) * mcols + c0 + col) * 8);
            *(uint4*)(lB + (size_t)idx * 8) = v;
        }
#pragma unroll
        for (int it = 0; it < 4; ++it) {
            int idx = it * 256 + tid;
            int p = idx >> 7, row = idx & 127;
            int grow = row0 + row; if (grow >= nrows) grow = nrows - 1;
            uint4 v;
            if (MODE != 1) {
                v = *(const uint4*)(A + (size_t)grow * astride + cb * 64 + p * 8);
            } else {
                if (cb < 64) {
                    int r = cb >> 2;
                    int i0 = ((cb & 3) << 6) + (p << 3);
                    v = *(const uint4*)(A + (size_t)grow * 256 + i0);
                    union { u16 u; _Float16 h; } mu; mu.u = MU[(size_t)grow * 16 + r];
                    union { uint4 u4; _Float16 h[8]; } wv; wv.u4 = v;
#pragma unroll
                    for (int j = 0; j < 8; ++j) wv.h[j] = wv.h[j] * mu.h;
                    v = wv.u4;
                } else if (cb < 68) {
                    int i0 = ((cb - 64) << 6) + (p << 3);
                    v = *(const uint4*)(A2 + (size_t)grow * 256 + i0);
                } else {
                    int j0 = p << 3;
                    if (j0 < 16) v = *(const uint4*)(MU + (size_t)grow * 16 + j0);
                    else v = (uint4){0, 0, 0, 0};
                }
            }
            *(uint4*)(lA + (size_t)idx * 8) = v;
        }
        __syncthreads();
#pragma unroll
        for (int kc = 0; kc < 2; ++kc) {
            int pp = kc * 4 + q;
            half8 af[4], bf[4];
#pragma unroll
            for (int mt = 0; mt < 4; ++mt)
                af[mt] = *(const half8*)(lA + ((size_t)pp * 128 + wm * 64 + mt * 16 + mm) * 8);
#pragma unroll
            for (int nt = 0; nt < 4; ++nt)
                bf[nt] = *(const half8*)(lB + ((size_t)pp * 128 + wn * 64 + nt * 16 + mm) * 8);
#pragma unroll
            for (int mt = 0; mt < 4; ++mt)
#pragma unroll
                for (int nt = 0; nt < 4; ++nt)
                    acc[mt][nt] = __builtin_amdgcn_mfma_f32_16x16x32_f16(af[mt], bf[nt], acc[mt][nt], 0, 0, 0);
        }
        __syncthreads();
    }

    // epilogue: C/D layout col=lane&15, row=q*4+reg
#pragma unroll
    for (int nt = 0; nt < 4; ++nt) {
        const int gcol = c0 + wn * 64 + nt * 16 + mm;
        float s = 0.f, ss = 0.f;
#pragma unroll
        for (int mt = 0; mt < 4; ++mt) {
#pragma unroll
            for (int r = 0; r < 4; ++r) {
                int grow = row0 + wm * 64 + mt * 16 + q * 4 + r;
                if (grow < nrows) {
                    float v = acc[mt][nt][r] + bias[gcol];
                    if (MODE == 0) {
                        v = fmaxf(v, 0.f);
                        outF[(size_t)grow * mcols + gcol] = v;
                        union { u16 u; _Float16 h; } cc; cc.h = (_Float16)v;
                        outH[(size_t)grow * mcols + gcol] = cc.u;
                    } else if (MODE == 1) {
                        union { u16 u; _Float16 h; } cc; cc.h = (_Float16)v;
                        outH[(size_t)grow * mcols + gcol] = cc.u;
                        s += v; ss += v * v;
                    } else {
                        v = fmaxf(v, 0.f);
                        union { u16 u; _Float16 h; } cc; cc.h = (_Float16)v;
                        outH[(size_t)grow * mcols + gcol] = cc.u;
                    }
                }
            }
        }
        if (MODE == 1) {
            // reduce over the 4 quad-lanes holding this column (lane XOR 16/32)
            s += __shfl_xor(s, 16);  s += __shfl_xor(s, 32);
            ss += __shfl_xor(ss, 16); ss += __shfl_xor(ss, 32);
            if (q == 0) {
                atomicAdd(&bnsum[gcol], s);
                atomicAdd(&bnsum[256 + gcol], ss);
            }
        }
    }
}

// ===========================================================================
// Fused BN-finalize + residual update (+ membership for next layer).
// alpha/shift recomputed per-thread from bnsum (3KB, L1-cached).
// ===========================================================================

template <int DOMEMB>
__global__ void update_k(const u16* __restrict__ pre16, const float* __restrict__ bnsum,
                         const float* __restrict__ gamma, const float* __restrict__ beta,
                         float* __restrict__ h, u16* __restrict__ h16,
                         const float* __restrict__ pcinv, const float* __restrict__ pcci,
                         const float* __restrict__ pccc,
                         u16* __restrict__ mu16, int* __restrict__ bflag, int n) {
    int lane = threadIdx.x & 63, wave = threadIdx.x >> 6;
    int node = blockIdx.x * 4 + wave;
    if (node >= n) return;
    int c = lane * 4;
    const float invn = 1.f / (float)n;
    float4 s4 = *(const float4*)(bnsum + c);
    float4 q4 = *(const float4*)(bnsum + 256 + c);
    float4 g4 = *(const float4*)(gamma + c);
    float4 b4 = *(const float4*)(beta + c);
    float m0 = s4.x * invn, m1 = s4.y * invn, m2 = s4.z * invn, m3 = s4.w * invn;
    float a0 = g4.x * rsqrtf(q4.x * invn - m0 * m0 + 1e-5f);
    float a1 = g4.y * rsqrtf(q4.y * invn - m1 * m1 + 1e-5f);
    float a2 = g4.z * rsqrtf(q4.z * invn - m2 * m2 + 1e-5f);
    float a3 = g4.w * rsqrtf(q4.w * invn - m3 * m3 + 1e-5f);
    float sh0 = b4.x - m0 * a0, sh1 = b4.y - m1 * a1;
    float sh2 = b4.z - m2 * a2, sh3 = b4.w - m3 * a3;

    size_t base = (size_t)node * 256 + c;
    union { uint2 u; _Float16 hh[4]; } p; p.u = *(const uint2*)(pre16 + base);
    float4 hv = *(const float4*)(h + base);
    float v0 = hv.x + fmaxf((float)p.hh[0] * a0 + sh0, 0.f);
    float v1 = hv.y + fmaxf((float)p.hh[1] * a1 + sh1, 0.f);
    float v2 = hv.z + fmaxf((float)p.hh[2] * a2 + sh2, 0.f);
    float v3 = hv.w + fmaxf((float)p.hh[3] * a3 + sh3, 0.f);
    *(float4*)(h + base) = (float4){v0, v1, v2, v3};
    union { uint2 u; _Float16 hh[4]; } o;
    o.hh[0] = (_Float16)v0; o.hh[1] = (_Float16)v1;
    o.hh[2] = (_Float16)v2; o.hh[3] = (_Float16)v3;
    *(uint2*)(h16 + base) = o.u;
    if (DOMEMB)
        membership_body(v0, v1, v2, v3, lane, node, pcinv, pcci, pccc, mu16, bflag);
}

// ===========================================================================
// Head: logits = q16 @ W_h2 + b_h2, softmax. One thread per node, W_h2 in LDS.
// ===========================================================================

__launch_bounds__(256)
__global__ void head_k(const u16* __restrict__ q16, const float* __restrict__ Wh2,
                       const float* __restrict__ bh2, float* __restrict__ out, int n) {
    __shared__ float W[5160];
    for (int i = threadIdx.x; i < 5160; i += 256)
        W[i] = (i < 5120) ? Wh2[i] : bh2[i - 5120];
    __syncthreads();
    int node = blockIdx.x * 256 + threadIdx.x;
    if (node >= n) return;
    float acc[40];
#pragma unroll
    for (int o = 0; o < 40; ++o) acc[o] = W[5120 + o];
    const u32* qp = (const u32*)(q16 + (size_t)node * 128);
    for (int k2 = 0; k2 < 64; ++k2) {
        union { u32 u; _Float16 h[2]; } qq; qq.u = qp[k2];
        float a = (float)qq.h[0], b = (float)qq.h[1];
        const float* w0 = W + (k2 * 2) * 40;
        const float* w1 = w0 + 40;
#pragma unroll
        for (int o = 0; o < 40; ++o) acc[o] += a * w0[o] + b * w1[o];
    }
    float mx = acc[0];
#pragma unroll
    for (int o = 1; o < 40; ++o) mx = fmaxf(mx, acc[o]);
    float s = 0.f;
#pragma unroll
    for (int o = 0; o < 40; ++o) { float e = expf(acc[o] - mx); acc[o] = e; s += e; }
    float is = 1.f / s;
    float* op = out + (size_t)node * 40;
#pragma unroll
    for (int o = 0; o < 40; ++o) op[o] = acc[o] * is;
}

// ===========================================================================
// Launch
// ===========================================================================

extern "C" void kernel_launch(void* const* d_in, const int* in_sizes, int n_in,
                              void* d_out, int out_size, void* d_ws, size_t ws_size,
                              hipStream_t stream) {
    const float* x       = (const float*)d_in[0];
    const int*   ei      = (const int*)d_in[1];
    const float* W_in    = (const float*)d_in[2];
    const float* b_in    = (const float*)d_in[3];
    const float* centers = (const float*)d_in[4];
    const float* logsig  = (const float*)d_in[5];
    const float* W_rule  = (const float*)d_in[6];
    const float* b_rule  = (const float*)d_in[7];
    const float* W_self  = (const float*)d_in[8];
    const float* b_self  = (const float*)d_in[9];
    const float* gamma   = (const float*)d_in[10];
    const float* beta    = (const float*)d_in[11];
    const float* W_h1    = (const float*)d_in[12];
    const float* b_h1    = (const float*)d_in[13];
    const float* W_h2    = (const float*)d_in[14];
    const float* b_h2    = (const float*)d_in[15];

    const int N = in_sizes[0] / 128;
    const int E = in_sizes[1] / 2;
    const int* e_src = ei;
    const int* e_dst = ei + E;

    char* w = (char*)d_ws;
    size_t off = 0;
    auto alloc = [&](size_t bytes) -> void* {
        void* p = w + off;
        off = (off + bytes + 255) & ~(size_t)255;
        return p;
    };

    u16*   x16    = (u16*)  alloc((size_t)N * 128 * 2);
    float* h      = (float*)alloc((size_t)N * 256 * 4);
    u16*   h16    = (u16*)  alloc((size_t)N * 256 * 2);
    u16*   pre16  = (u16*)  alloc((size_t)N * 256 * 2);
    u16*   agg16  = (u16*)  alloc((size_t)N * 256 * 2);
    u16*   mu16   = (u16*)  alloc((size_t)N * 16 * 2);
    u16*   q16    = (u16*)  alloc((size_t)N * 128 * 2);
    u16*   wcat   = (u16*)  alloc((size_t)3 * 552 * 256 * 8 * 2);
    u16*   winp   = (u16*)  alloc((size_t)16 * 256 * 8 * 2);
    u16*   wh1p   = (u16*)  alloc((size_t)32 * 128 * 8 * 2);
    float* pcinv  = (float*)alloc((size_t)48 * 256 * 4);
    float* pcci   = (float*)alloc((size_t)48 * 256 * 4);
    float* pccc   = (float*)alloc((size_t)48 * 4);
    int*   indptr = (int*)  alloc((size_t)(N + 1) * 4);
    int*   cursor = (int*)  alloc((size_t)N * 4);
    float* deginv = (float*)alloc((size_t)N * 4);
    int*   ssrc   = (int*)  alloc((size_t)E * 4);
    // zero region: [deg N][bflag 3*512][bnsum 3*512][csr_done pad]
    const int nzero = N + 3 * 512 + 3 * 512 + 64;
    int*   zerob  = (int*)  alloc((size_t)nzero * 4);
    int*   deg    = zerob;
    int*   bflagA = zerob + N;
    float* bnsumA = (float*)(zerob + N + 3 * 512);
    int*   done   = zerob + N + 3 * 512 + 3 * 512;

    const int Z = cdiv(nzero, 256);
    const int C = cdiv(N * 32, 256);
    const int Wb = 3 * 552 * 256 * 8 / 256;   // 13248
    const int prep_grid = Z + C + Wb + 128 + 128 + 48;
    const int gx = cdiv(N, 128);

    prep_k<<<prep_grid, 256, 0, stream>>>(x, W_rule, W_self, b_rule, W_in, W_h1,
                                          centers, logsig, x16, wcat, winp, wh1p,
                                          pcinv, pcci, pccc, zerob, nzero, Z, C, Wb, N);

    gemm_k<0, 2><<<dim3(gx, 2), 256, 0, stream>>>(x16, nullptr, nullptr, winp, b_in,
                                                  nullptr, h, h16, nullptr, N, 256, 128);
    membership_k<<<cdiv(N, 4), 256, 0, stream>>>(h16, pcinv, pcci, pccc, mu16, bflagA, N);

    for (int l = 0; l < 3; ++l) {
        int* bf = bflagA + l * 512;
        int* bany = bf + 511;
        float* bns = bnsumA + l * 512;
        deg_count_g<<<cdiv(E, 256), 256, 0, stream>>>(e_dst, deg, bany, done, E);
        csr_scan_g<<<1, 1024, 0, stream>>>(deg, indptr, cursor, deginv, bany, done, N);
        edge_scatter_g<<<cdiv(E, 256), 256, 0, stream>>>(e_src, e_dst, cursor, ssrc, bany, done, E);
        agg_k<<<1024, 256, 0, stream>>>(h16, indptr, ssrc, deginv, bf, done, agg16, N);
        gemm_k<1, 69><<<dim3(gx, 2), 256, 0, stream>>>(agg16, h16, mu16,
                                                       wcat + (size_t)l * 552 * 256 * 8,
                                                       b_self + l * 256, bf, nullptr, pre16,
                                                       bns, N, 256, 0);
        if (l < 2) {
            update_k<1><<<cdiv(N, 4), 256, 0, stream>>>(pre16, bns, gamma + l * 256,
                                                        beta + l * 256, h, h16,
                                                        pcinv + (size_t)(l + 1) * 16 * 256,
                                                        pcci + (size_t)(l + 1) * 16 * 256,
                                                        pccc + (l + 1) * 16, mu16,
                                                        bflagA + (l + 1) * 512, N);
        } else {
            update_k<0><<<cdiv(N, 4), 256, 0, stream>>>(pre16, bns, gamma + l * 256,
                                                        beta + l * 256, h, h16,
                                                        nullptr, nullptr, nullptr,
                                                        nullptr, nullptr, N);
        }
    }

    gemm_k<2, 4><<<dim3(gx, 1), 256, 0, stream>>>(h16, nullptr, nullptr, wh1p, b_h1,
                                                  nullptr, nullptr, q16, nullptr, N, 128, 256);
    head_k<<<cdiv(N, 256), 256, 0, stream>>>(q16, W_h2, b_h2, (float*)d_out, N);
}

// Round 4
// 500.752 us; speedup vs baseline: 2.3783x; 1.1886x over previous
//
#include <hip/hip_runtime.h>
#include <hip/hip_fp16.h>
#include <cstdint>
#include <cstddef>

using u16 = unsigned short;
using u32 = unsigned int;

typedef _Float16 half8 __attribute__((ext_vector_type(8)));
typedef float f32x4 __attribute__((ext_vector_type(4)));

static inline int cdiv(int a, int b) { return (a + b - 1) / b; }

// ===========================================================================
// prep_k: fused zero-init + f16 cast + weight panelization + rule precompute.
// ===========================================================================

__global__ void prep_k(const float* __restrict__ x, const float* __restrict__ Wr,
                       const float* __restrict__ Ws, const float* __restrict__ br,
                       const float* __restrict__ W_in, const float* __restrict__ W_h1,
                       const float* __restrict__ centers, const float* __restrict__ logsig,
                       u16* __restrict__ x16, u16* __restrict__ wcat,
                       u16* __restrict__ winp, u16* __restrict__ wh1p,
                       u16* __restrict__ pcB, float* __restrict__ pccc,
                       int* __restrict__ zerobase, int nzero,
                       int Z, int C, int Wb, int N) {
    const int bid = blockIdx.x;
    const int tid = threadIdx.x;
    if (bid < Z) {                                   // zero-init region
        int i = bid * 256 + tid;
        if (i < nzero) zerobase[i] = 0;
        return;
    }
    if (bid < Z + C) {                               // x -> f16
        size_t i = (size_t)(bid - Z) * 256 + tid;
        if (i >= (size_t)N * 32) return;
        float4 v = *(const float4*)(x + i * 4);
        union { uint2 u; _Float16 h[4]; } o;
        o.h[0] = (_Float16)v.x; o.h[1] = (_Float16)v.y;
        o.h[2] = (_Float16)v.z; o.h[3] = (_Float16)v.w;
        *(uint2*)(x16 + i * 4) = o.u;
        return;
    }
    if (bid < Z + C + Wb) {                          // wcat panels [552][256][8] x3 layers
        size_t t = (size_t)(bid - Z - C) * 256 + tid;
        const size_t PL = 552u * 256u * 8u;
        int l = (int)(t / PL);
        size_t rem = t - (size_t)l * PL;
        int kp = (int)(rem >> 11);
        int o = (int)((rem >> 3) & 255);
        int e = (int)(rem & 7);
        int k = kp * 8 + e;
        float v;
        if (k < 4096)      v = Wr[((((size_t)l * 16 + (k >> 8)) * 256) + (k & 255)) * 256 + o];
        else if (k < 4352) v = Ws[(((size_t)l * 256) + (k - 4096)) * 256 + o];
        else if (k < 4368) v = br[(((size_t)l * 16) + (k - 4352)) * 256 + o];
        else               v = 0.f;
        union { u16 u; _Float16 h; } c; c.h = (_Float16)v;
        wcat[t] = c.u;
        return;
    }
    if (bid < Z + C + Wb + 128) {                    // panelize W_in (K=128,M=256)
        size_t t = (size_t)(bid - Z - C - Wb) * 256 + tid;
        int e = (int)(t & 7), o = (int)((t >> 3) & 255);
        int kp = (int)(t >> 11);
        union { u16 u; _Float16 h; } c; c.h = (_Float16)W_in[(size_t)(kp * 8 + e) * 256 + o];
        winp[t] = c.u;
        return;
    }
    if (bid < Z + C + Wb + 256) {                    // panelize W_h1 (K=256,M=128)
        size_t t = (size_t)(bid - Z - C - Wb - 128) * 256 + tid;
        int e = (int)(t & 7), o = (int)((t >> 3) & 127);
        int kp = (int)(t >> 10);
        union { u16 u; _Float16 h; } c; c.h = (_Float16)W_h1[(size_t)(kp * 8 + e) * 128 + o];
        wh1p[t] = c.u;
        return;
    }
    {                                                // pc_build: 48 blocks (l*16+r)
        int lr = bid - (Z + C + Wb + 256);
        size_t idx = (size_t)lr * 256 + tid;
        float ls = logsig[idx];
        float inv = expf(-2.f * ls);
        float c = centers[idx];
        union { u16 u; _Float16 h; } c1, c2;
        c1.h = (_Float16)inv;
        c2.h = (_Float16)(-2.f * c * inv);
        pcB[(size_t)lr * 512 + tid] = c1.u;          // B[k][r] = inv_s2[r][k], k<256
        pcB[(size_t)lr * 512 + 256 + tid] = c2.u;    // B[256+k][r] = -2 c inv
        __shared__ float sm[256];
        sm[tid] = c * c * inv;
        __syncthreads();
        for (int s = 128; s > 0; s >>= 1) { if (tid < s) sm[tid] += sm[tid + s]; __syncthreads(); }
        if (tid == 0) pccc[lr] = sm[0];
    }
}

// ===========================================================================
// Gated CSR build: runs only if (bany[l] && !csr_done). agg_k sets csr_done.
// ===========================================================================

__global__ void deg_count_g(const int* __restrict__ dst, int* __restrict__ deg,
                            const int* __restrict__ bany, const int* __restrict__ done, int E) {
    if (*bany == 0 || *done != 0) return;
    for (int e = blockIdx.x * 256 + threadIdx.x; e < E; e += gridDim.x * 256)
        atomicAdd(&deg[dst[e]], 1);
}

__global__ void csr_scan_g(const int* __restrict__ deg, int* __restrict__ indptr,
                           int* __restrict__ cursor, float* __restrict__ deginv,
                           const int* __restrict__ bany, const int* __restrict__ done, int n) {
    if (*bany == 0 || *done != 0) return;
    const int tid = threadIdx.x;   // 1024 threads, 1 block (cold path only)
    const int chunk = (n + 1023) >> 10;
    int s0 = tid * chunk, s1 = s0 + chunk; if (s1 > n) s1 = n; if (s0 > n) s0 = n;
    int tot = 0;
    for (int i = s0; i < s1; ++i) tot += deg[i];
    __shared__ int sm[1024];
    sm[tid] = tot; __syncthreads();
    for (int off = 1; off < 1024; off <<= 1) {
        int t = (tid >= off) ? sm[tid - off] : 0;
        __syncthreads(); sm[tid] += t; __syncthreads();
    }
    int base = sm[tid] - tot;
    for (int i = s0; i < s1; ++i) {
        int d = deg[i];
        indptr[i] = base; cursor[i] = base;
        deginv[i] = 1.f / (float)(d > 1 ? d : 1);
        base += d;
    }
    if (tid == 1023) indptr[n] = sm[1023];
}

__global__ void edge_scatter_g(const int* __restrict__ src, const int* __restrict__ dst,
                               int* __restrict__ cursor, int* __restrict__ ssrc,
                               const int* __restrict__ bany, const int* __restrict__ done, int E) {
    if (*bany == 0 || *done != 0) return;
    for (int e = blockIdx.x * 256 + threadIdx.x; e < E; e += gridDim.x * 256) {
        int d = dst[e];
        int pos = atomicAdd(&cursor[d], 1);
        ssrc[pos] = src[e];
    }
}

// ===========================================================================
// MFMA membership: d = [h^2 | h] @ pcB + cc, firing = exp(-0.5 d), mu = norm.
// Per wave: 16 nodes. A-frag: lane m=lane&15 -> node, k=q*8+j (squared for k<256).
// C layout: col=rule=lane&15, row=node=q*4+reg -> rule-normalize via 4 shuffles.
// ===========================================================================

__launch_bounds__(256)
__global__ void memb_k(const u16* __restrict__ h16, const u16* __restrict__ pcB,
                       const float* __restrict__ pccc,
                       u16* __restrict__ mu16, int* __restrict__ bflag, int n) {
    const int lane = threadIdx.x & 63, wave = threadIdx.x >> 6;
    const int q = lane >> 4, mm = lane & 15;
    const int n0 = (blockIdx.x * 4 + wave) * 16;
    int nodeA = n0 + mm; if (nodeA >= n) nodeA = n - 1;
    const u16* hrow = h16 + (size_t)nodeA * 256;
    const u16* brow = pcB + (size_t)mm * 512;
    f32x4 acc = (f32x4){0.f, 0.f, 0.f, 0.f};
#pragma unroll
    for (int it = 0; it < 16; ++it) {
        int k = it * 32 + q * 8;
        half8 b = *(const half8*)(brow + k);
        half8 a;
        if (k < 256) {
            a = *(const half8*)(hrow + k);
            a = a * a;                               // v_pk_mul_f16 x4
        } else {
            a = *(const half8*)(hrow + (k - 256));
        }
        acc = __builtin_amdgcn_mfma_f32_16x16x32_f16(a, b, acc, 0, 0, 0);
    }
    float cc = pccc[mm];
    bool any = false;
#pragma unroll
    for (int r = 0; r < 4; ++r) {
        float d = acc[r] + cc;
        float f = expf(-0.5f * d);
        float s = f;
        s += __shfl_xor(s, 1); s += __shfl_xor(s, 2);
        s += __shfl_xor(s, 4); s += __shfl_xor(s, 8);
        int node = n0 + q * 4 + r;
        if (node < n) {
            union { u16 u; _Float16 h; } c2;
            c2.h = (_Float16)(f / (s + 1e-12f));
            mu16[(size_t)node * 16 + mm] = c2.u;
            if (s > 0.f) any = true;
        }
    }
    if (any && mm == 0) {
        atomicOr(&bflag[n0 >> 7], 1);    // n0..n0+15 share the same 128-block
        atomicOr(&bflag[511], 1);
    }
}

// ===========================================================================
// Neighbor mean (grid-stride; early-exits unless this layer fired).
// ===========================================================================

__global__ void agg_k(const u16* __restrict__ h16, const int* __restrict__ indptr,
                      const int* __restrict__ ssrc, const float* __restrict__ deginv,
                      const int* __restrict__ bflag, int* __restrict__ done,
                      u16* __restrict__ agg16, int n) {
    if (bflag[511] == 0) return;
    if (blockIdx.x == 0 && threadIdx.x == 0 && *done == 0) *done = 1;
    int lane = threadIdx.x & 63, wave = threadIdx.x >> 6;
    for (int node = blockIdx.x * 4 + wave; node < n; node += gridDim.x * 4) {
        if (bflag[node >> 7] == 0) continue;
        int j0 = indptr[node], j1 = indptr[node + 1];
        float a0 = 0, a1 = 0, a2 = 0, a3 = 0;
        for (int j = j0; j < j1; ++j) {
            int sN = ssrc[j];
            union { uint2 u; _Float16 h[4]; } hv;
            hv.u = *(const uint2*)(h16 + (size_t)sN * 256 + lane * 4);
            a0 += (float)hv.h[0]; a1 += (float)hv.h[1];
            a2 += (float)hv.h[2]; a3 += (float)hv.h[3];
        }
        float di = deginv[node];
        union { uint2 u; _Float16 h[4]; } o;
        o.h[0] = (_Float16)(a0 * di); o.h[1] = (_Float16)(a1 * di);
        o.h[2] = (_Float16)(a2 * di); o.h[3] = (_Float16)(a3 * di);
        *(uint2*)(agg16 + (size_t)node * 256 + lane * 4) = o.u;
    }
}

// ===========================================================================
// Unified f16 MFMA GEMM. 128x128 tile, BK=64, 256 threads (4 waves).
// MODE 0: h = relu(x16 @ Winp + b_in)   (K=128)  -> h f32 + h16
// MODE 1: pre16 = [mu*agg | h | mu]@Wcat + b_self; BN stats fused via atomics.
// MODE 2: q16 = relu(h16 @ Wh1p + b_h1) (K=256)
// ===========================================================================

template <int MODE, int NCHUNK>
__launch_bounds__(256, 2)
__global__ void gemm_k(const u16* __restrict__ A, const u16* __restrict__ A2,
                       const u16* __restrict__ MU, const u16* __restrict__ Bp,
                       const float* __restrict__ bias, const int* __restrict__ bflag,
                       float* __restrict__ outF, u16* __restrict__ outH,
                       float* __restrict__ bnsum,
                       int nrows, int mcols, int astride) {
    __shared__ __align__(16) u16 lA[8192];
    __shared__ __align__(16) u16 lB[8192];
    const int tid = threadIdx.x;
    const int row0 = blockIdx.x * 128;
    const int c0 = blockIdx.y * 128;
    const int lane = tid & 63;
    const int q = lane >> 4, mm = lane & 15;
    const int wave = tid >> 6;
    const int wm = wave >> 1, wn = wave & 1;

    f32x4 acc[4][4];
#pragma unroll
    for (int i = 0; i < 4; ++i)
#pragma unroll
        for (int j = 0; j < 4; ++j) acc[i][j] = (f32x4){0.f, 0.f, 0.f, 0.f};

    int cb = 0, cbEnd = NCHUNK;
    if (MODE == 1 && bflag[blockIdx.x] == 0) { cb = 64; cbEnd = 68; }  // mu==0: fuzzy+mu K exact-zero

    for (; cb < cbEnd; ++cb) {
#pragma unroll
        for (int it = 0; it < 4; ++it) {
            int idx = it * 256 + tid;
            int p = idx >> 7, col = idx & 127;
            uint4 v = *(const uint4*)(Bp + (((size_t)(cb * 8 + p)) * mcols + c0 + col) * 8);
            *(uint4*)(lB + (size_t)idx * 8) = v;
        }
#pragma unroll
        for (int it = 0; it < 4; ++it) {
            int idx = it * 256 + tid;
            int p = idx >> 7, row = idx & 127;
            int grow = row0 + row; if (grow >= nrows) grow = nrows - 1;
            uint4 v;
            if (MODE != 1) {
                v = *(const uint4*)(A + (size_t)grow * astride + cb * 64 + p * 8);
            } else {
                if (cb < 64) {
                    int r = cb >> 2;
                    int i0 = ((cb & 3) << 6) + (p << 3);
                    v = *(const uint4*)(A + (size_t)grow * 256 + i0);
                    union { u16 u; _Float16 h; } mu; mu.u = MU[(size_t)grow * 16 + r];
                    union { uint4 u4; _Float16 h[8]; } wv; wv.u4 = v;
#pragma unroll
                    for (int j = 0; j < 8; ++j) wv.h[j] = wv.h[j] * mu.h;
                    v = wv.u4;
                } else if (cb < 68) {
                    int i0 = ((cb - 64) << 6) + (p << 3);
                    v = *(const uint4*)(A2 + (size_t)grow * 256 + i0);
                } else {
                    int j0 = p << 3;
                    if (j0 < 16) v = *(const uint4*)(MU + (size_t)grow * 16 + j0);
                    else v = (uint4){0, 0, 0, 0};
                }
            }
            *(uint4*)(lA + (size_t)idx * 8) = v;
        }
        __syncthreads();
#pragma unroll
        for (int kc = 0; kc < 2; ++kc) {
            int pp = kc * 4 + q;
            half8 af[4], bf[4];
#pragma unroll
            for (int mt = 0; mt < 4; ++mt)
                af[mt] = *(const half8*)(lA + ((size_t)pp * 128 + wm * 64 + mt * 16 + mm) * 8);
#pragma unroll
            for (int nt = 0; nt < 4; ++nt)
                bf[nt] = *(const half8*)(lB + ((size_t)pp * 128 + wn * 64 + nt * 16 + mm) * 8);
#pragma unroll
            for (int mt = 0; mt < 4; ++mt)
#pragma unroll
                for (int nt = 0; nt < 4; ++nt)
                    acc[mt][nt] = __builtin_amdgcn_mfma_f32_16x16x32_f16(af[mt], bf[nt], acc[mt][nt], 0, 0, 0);
        }
        __syncthreads();
    }

    // epilogue: C/D layout col=lane&15, row=q*4+reg
#pragma unroll
    for (int nt = 0; nt < 4; ++nt) {
        const int gcol = c0 + wn * 64 + nt * 16 + mm;
        float s = 0.f, ss = 0.f;
#pragma unroll
        for (int mt = 0; mt < 4; ++mt) {
#pragma unroll
            for (int r = 0; r < 4; ++r) {
                int grow = row0 + wm * 64 + mt * 16 + q * 4 + r;
                if (grow < nrows) {
                    float v = acc[mt][nt][r] + bias[gcol];
                    if (MODE == 0) {
                        v = fmaxf(v, 0.f);
                        outF[(size_t)grow * mcols + gcol] = v;
                        union { u16 u; _Float16 h; } cc; cc.h = (_Float16)v;
                        outH[(size_t)grow * mcols + gcol] = cc.u;
                    } else if (MODE == 1) {
                        union { u16 u; _Float16 h; } cc; cc.h = (_Float16)v;
                        outH[(size_t)grow * mcols + gcol] = cc.u;
                        s += v; ss += v * v;
                    } else {
                        v = fmaxf(v, 0.f);
                        union { u16 u; _Float16 h; } cc; cc.h = (_Float16)v;
                        outH[(size_t)grow * mcols + gcol] = cc.u;
                    }
                }
            }
        }
        if (MODE == 1) {
            s += __shfl_xor(s, 16);  s += __shfl_xor(s, 32);
            ss += __shfl_xor(ss, 16); ss += __shfl_xor(ss, 32);
            if (q == 0) {
                atomicAdd(&bnsum[gcol], s);
                atomicAdd(&bnsum[256 + gcol], ss);
            }
        }
    }
}

// ===========================================================================
// Fused BN-finalize + residual update. Coeffs hoisted; grid-stride over nodes.
// ===========================================================================

__global__ void update_k(const u16* __restrict__ pre16, const float* __restrict__ bnsum,
                         const float* __restrict__ gamma, const float* __restrict__ beta,
                         float* __restrict__ h, u16* __restrict__ h16, int n) {
    int lane = threadIdx.x & 63, wave = threadIdx.x >> 6;
    int c = lane * 4;
    const float invn = 1.f / (float)n;
    float4 s4 = *(const float4*)(bnsum + c);
    float4 q4 = *(const float4*)(bnsum + 256 + c);
    float4 g4 = *(const float4*)(gamma + c);
    float4 b4 = *(const float4*)(beta + c);
    float m0 = s4.x * invn, m1 = s4.y * invn, m2 = s4.z * invn, m3 = s4.w * invn;
    float a0 = g4.x * rsqrtf(q4.x * invn - m0 * m0 + 1e-5f);
    float a1 = g4.y * rsqrtf(q4.y * invn - m1 * m1 + 1e-5f);
    float a2 = g4.z * rsqrtf(q4.z * invn - m2 * m2 + 1e-5f);
    float a3 = g4.w * rsqrtf(q4.w * invn - m3 * m3 + 1e-5f);
    float sh0 = b4.x - m0 * a0, sh1 = b4.y - m1 * a1;
    float sh2 = b4.z - m2 * a2, sh3 = b4.w - m3 * a3;

    for (int node = blockIdx.x * 4 + wave; node < n; node += gridDim.x * 4) {
        size_t base = (size_t)node * 256 + c;
        union { uint2 u; _Float16 hh[4]; } p; p.u = *(const uint2*)(pre16 + base);
        float4 hv = *(const float4*)(h + base);
        float v0 = hv.x + fmaxf((float)p.hh[0] * a0 + sh0, 0.f);
        float v1 = hv.y + fmaxf((float)p.hh[1] * a1 + sh1, 0.f);
        float v2 = hv.z + fmaxf((float)p.hh[2] * a2 + sh2, 0.f);
        float v3 = hv.w + fmaxf((float)p.hh[3] * a3 + sh3, 0.f);
        *(float4*)(h + base) = (float4){v0, v1, v2, v3};
        union { uint2 u; _Float16 hh[4]; } o;
        o.hh[0] = (_Float16)v0; o.hh[1] = (_Float16)v1;
        o.hh[2] = (_Float16)v2; o.hh[3] = (_Float16)v3;
        *(uint2*)(h16 + base) = o.u;
    }
}

// ===========================================================================
// Head: logits = q16 @ W_h2 + b_h2, softmax. One thread per node, W_h2 in LDS.
// ===========================================================================

__launch_bounds__(256)
__global__ void head_k(const u16* __restrict__ q16, const float* __restrict__ Wh2,
                       const float* __restrict__ bh2, float* __restrict__ out, int n) {
    __shared__ float W[5160];
    for (int i = threadIdx.x; i < 5160; i += 256)
        W[i] = (i < 5120) ? Wh2[i] : bh2[i - 5120];
    __syncthreads();
    int node = blockIdx.x * 256 + threadIdx.x;
    if (node >= n) return;
    float acc[40];
#pragma unroll
    for (int o = 0; o < 40; ++o) acc[o] = W[5120 + o];
    const u32* qp = (const u32*)(q16 + (size_t)node * 128);
    for (int k2 = 0; k2 < 64; ++k2) {
        union { u32 u; _Float16 h[2]; } qq; qq.u = qp[k2];
        float a = (float)qq.h[0], b = (float)qq.h[1];
        const float* w0 = W + (k2 * 2) * 40;
        const float* w1 = w0 + 40;
#pragma unroll
        for (int o = 0; o < 40; ++o) acc[o] += a * w0[o] + b * w1[o];
    }
    float mx = acc[0];
#pragma unroll
    for (int o = 1; o < 40; ++o) mx = fmaxf(mx, acc[o]);
    float s = 0.f;
#pragma unroll
    for (int o = 0; o < 40; ++o) { float e = expf(acc[o] - mx); acc[o] = e; s += e; }
    float is = 1.f / s;
    float* op = out + (size_t)node * 40;
#pragma unroll
    for (int o = 0; o < 40; ++o) op[o] = acc[o] * is;
}

// ===========================================================================
// Launch
// ===========================================================================

extern "C" void kernel_launch(void* const* d_in, const int* in_sizes, int n_in,
                              void* d_out, int out_size, void* d_ws, size_t ws_size,
                              hipStream_t stream) {
    const float* x       = (const float*)d_in[0];
    const int*   ei      = (const int*)d_in[1];
    const float* W_in    = (const float*)d_in[2];
    const float* b_in    = (const float*)d_in[3];
    const float* centers = (const float*)d_in[4];
    const float* logsig  = (const float*)d_in[5];
    const float* W_rule  = (const float*)d_in[6];
    const float* b_rule  = (const float*)d_in[7];
    const float* W_self  = (const float*)d_in[8];
    const float* b_self  = (const float*)d_in[9];
    const float* gamma   = (const float*)d_in[10];
    const float* beta    = (const float*)d_in[11];
    const float* W_h1    = (const float*)d_in[12];
    const float* b_h1    = (const float*)d_in[13];
    const float* W_h2    = (const float*)d_in[14];
    const float* b_h2    = (const float*)d_in[15];

    const int N = in_sizes[0] / 128;
    const int E = in_sizes[1] / 2;
    const int* e_src = ei;
    const int* e_dst = ei + E;

    char* w = (char*)d_ws;
    size_t off = 0;
    auto alloc = [&](size_t bytes) -> void* {
        void* p = w + off;
        off = (off + bytes + 255) & ~(size_t)255;
        return p;
    };

    u16*   x16    = (u16*)  alloc((size_t)N * 128 * 2);
    float* h      = (float*)alloc((size_t)N * 256 * 4);
    u16*   h16    = (u16*)  alloc((size_t)N * 256 * 2);
    u16*   pre16  = (u16*)  alloc((size_t)N * 256 * 2);
    u16*   agg16  = (u16*)  alloc((size_t)N * 256 * 2);
    u16*   mu16   = (u16*)  alloc((size_t)N * 16 * 2);
    u16*   q16    = (u16*)  alloc((size_t)N * 128 * 2);
    u16*   wcat   = (u16*)  alloc((size_t)3 * 552 * 256 * 8 * 2);
    u16*   winp   = (u16*)  alloc((size_t)16 * 256 * 8 * 2);
    u16*   wh1p   = (u16*)  alloc((size_t)32 * 128 * 8 * 2);
    u16*   pcB    = (u16*)  alloc((size_t)48 * 512 * 2);
    float* pccc   = (float*)alloc((size_t)48 * 4);
    int*   indptr = (int*)  alloc((size_t)(N + 1) * 4);
    int*   cursor = (int*)  alloc((size_t)N * 4);
    float* deginv = (float*)alloc((size_t)N * 4);
    int*   ssrc   = (int*)  alloc((size_t)E * 4);
    // zero region: [deg N][bflag 3*512][bnsum 3*512][csr_done pad]
    const int nzero = N + 3 * 512 + 3 * 512 + 64;
    int*   zerob  = (int*)  alloc((size_t)nzero * 4);
    int*   deg    = zerob;
    int*   bflagA = zerob + N;
    float* bnsumA = (float*)(zerob + N + 3 * 512);
    int*   done   = zerob + N + 3 * 512 + 3 * 512;

    const int Z = cdiv(nzero, 256);
    const int C = cdiv(N * 32, 256);
    const int Wb = 3 * 552 * 256 * 8 / 256;   // 13248
    const int prep_grid = Z + C + Wb + 128 + 128 + 48;
    const int gx = cdiv(N, 128);

    prep_k<<<prep_grid, 256, 0, stream>>>(x, W_rule, W_self, b_rule, W_in, W_h1,
                                          centers, logsig, x16, wcat, winp, wh1p,
                                          pcB, pccc, zerob, nzero, Z, C, Wb, N);

    gemm_k<0, 2><<<dim3(gx, 2), 256, 0, stream>>>(x16, nullptr, nullptr, winp, b_in,
                                                  nullptr, h, h16, nullptr, N, 256, 128);
    memb_k<<<cdiv(N, 64), 256, 0, stream>>>(h16, pcB, pccc, mu16, bflagA, N);

    for (int l = 0; l < 3; ++l) {
        int* bf = bflagA + l * 512;
        int* bany = bf + 511;
        float* bns = bnsumA + l * 512;
        deg_count_g<<<1024, 256, 0, stream>>>(e_dst, deg, bany, done, E);
        csr_scan_g<<<1, 1024, 0, stream>>>(deg, indptr, cursor, deginv, bany, done, N);
        edge_scatter_g<<<1024, 256, 0, stream>>>(e_src, e_dst, cursor, ssrc, bany, done, E);
        agg_k<<<1024, 256, 0, stream>>>(h16, indptr, ssrc, deginv, bf, done, agg16, N);
        gemm_k<1, 69><<<dim3(gx, 2), 256, 0, stream>>>(agg16, h16, mu16,
                                                       wcat + (size_t)l * 552 * 256 * 8,
                                                       b_self + l * 256, bf, nullptr, pre16,
                                                       bns, N, 256, 0);
        update_k<<<3125, 256, 0, stream>>>(pre16, bns, gamma + l * 256, beta + l * 256,
                                           h, h16, N);
        if (l < 2)
            memb_k<<<cdiv(N, 64), 256, 0, stream>>>(h16, pcB + (size_t)(l + 1) * 16 * 512,
                                                    pccc + (l + 1) * 16, mu16,
                                                    bflagA + (l + 1) * 512, N);
    }

    gemm_k<2, 4><<<dim3(gx, 1), 256, 0, stream>>>(h16, nullptr, nullptr, wh1p, b_h1,
                                                  nullptr, nullptr, q16, nullptr, N, 128, 256);
    head_k<<<cdiv(N, 256), 256, 0, stream>>>(q16, W_h2, b_h2, (float*)d_out, N);
}